// Round 5
// baseline (694.446 us; speedup 1.0000x reference)
//
#include <hip/hip_runtime.h>
#include <hip/hip_bf16.h>

// N = 100000, E = 1600000, IN = 128, H = 4, D = 32
//
// Math (validated rounds 1-4, absmax 9.8e-4 vs threshold 8.2e-3):
//   vbar[n]  = xs[n] @ WT^T + bvbar          (WT[d][i] = 0.25*sum_h Wv[i][32h+d])
//   vbar2[n] = vbar[n] * (deg[n]? rsqrt(deg[n]) : 0)
//   cst[d]   = mean_n vbar[n,d]
//   out[n,d] = cst[d] + (deg[n]? rsqrt(deg[n]):0) * sum_{e:col=n} vbar2[row_e, d]
//
// Round-5 structure: 128-col buckets; XCD-local ticketed fill (full-line write
// accumulation in each XCD's L2); fused per-bucket LDS gather.
// Pack: meta = row | (col&127)<<20  (requires N <= 2^20).

#define GRID_EDGE 1024

// ---------------------------------------------------------------------------
// K0: WTP[i4][d] (float4 over IN): WTP[i4*32+d] = {wt(4i4+j,d)}_{j=0..3},
//     wt(i,d) = 0.25*sum_h Wv[i*128+32h+d]
// ---------------------------------------------------------------------------
__global__ __launch_bounds__(256) void wt_kernel(const float* __restrict__ Wv,
                                                 float4* __restrict__ WTP) {
    int idx = blockIdx.x * 256 + threadIdx.x;
    if (idx < 1024) {
        int i4 = idx >> 5, d = idx & 31;
        float c[4];
#pragma unroll
        for (int j = 0; j < 4; j++) {
            int i = i4 * 4 + j;
            c[j] = 0.25f * (Wv[i * 128 + d] + Wv[i * 128 + 32 + d] +
                            Wv[i * 128 + 64 + d] + Wv[i * 128 + 96 + d]);
        }
        WTP[idx] = make_float4(c[0], c[1], c[2], c[3]);
    }
}

// ---------------------------------------------------------------------------
// K1: deg histogram + per-(bucket, writer&7) edge counts
// ---------------------------------------------------------------------------
__global__ __launch_bounds__(256) void hist_kernel(const int* __restrict__ ei, int E,
                                                   int chunk, unsigned* __restrict__ deg,
                                                   unsigned* __restrict__ bcnt8) {
    const int e0 = blockIdx.x * chunk;
    const int e1 = min(E, e0 + chunk);
    const int x = blockIdx.x & 7;
    for (int e = e0 + threadIdx.x; e < e1; e += 256) {
        int col = ei[E + e];
        atomicAdd(&deg[col], 1u);
        atomicAdd(&bcnt8[(col >> 7) * 8 + x], 1u);
    }
}

// ---------------------------------------------------------------------------
// K2: vbar2 = (xs @ WT^T + bvbar) * rsqrt(deg)  +  column-sum partials.
// LDS-free: per 32-lane group, 4 nodes; x via broadcast float4 loads,
// WTP via coalesced per-lane loads (L1-hot). One wave = 8-node tiles,
// grid-stride by wave, no barriers in the loop.
// ---------------------------------------------------------------------------
__global__ __launch_bounds__(256) void vbar_kernel(
    const float* __restrict__ xs, const float4* __restrict__ WTP,
    const float* __restrict__ bv, const unsigned* __restrict__ deg,
    float* __restrict__ vbar2, float* __restrict__ g_csum, int N)
{
    __shared__ float red[256];
    const int tid = threadIdx.x;
    const int wave = tid >> 6, lane = tid & 63;
    const int g = lane >> 5, d = lane & 31;
    const float bvbar = 0.25f * (bv[d] + bv[32 + d] + bv[64 + d] + bv[96 + d]);
    float csum = 0.f;

    const int ntiles = (N + 7) >> 3;
    const int wglob = blockIdx.x * 4 + wave;
    const int nwaves = gridDim.x * 4;

    for (int t = wglob; t < ntiles; t += nwaves) {
        const int nr = t * 8 + g * 4;   // this group's 4 rows
        float a0 = bvbar, a1 = bvbar, a2 = bvbar, a3 = bvbar;
        if (nr + 3 < N) {
            const float* xb = xs + (size_t)nr * 128;
#pragma unroll 8
            for (int i4 = 0; i4 < 32; i4++) {
                float4 w = WTP[i4 * 32 + d];
                float4 x0 = *(const float4*)(xb + i4 * 4);
                float4 x1 = *(const float4*)(xb + 128 + i4 * 4);
                float4 x2 = *(const float4*)(xb + 256 + i4 * 4);
                float4 x3 = *(const float4*)(xb + 384 + i4 * 4);
                a0 += x0.x * w.x + x0.y * w.y + x0.z * w.z + x0.w * w.w;
                a1 += x1.x * w.x + x1.y * w.y + x1.z * w.z + x1.w * w.w;
                a2 += x2.x * w.x + x2.y * w.y + x2.z * w.z + x2.w * w.w;
                a3 += x3.x * w.x + x3.y * w.y + x3.z * w.z + x3.w * w.w;
            }
            csum += a0 + a1 + a2 + a3;
            unsigned u0 = deg[nr + 0], u1 = deg[nr + 1], u2 = deg[nr + 2], u3 = deg[nr + 3];
            vbar2[(size_t)(nr + 0) * 32 + d] = u0 ? a0 * rsqrtf((float)u0) : 0.f;
            vbar2[(size_t)(nr + 1) * 32 + d] = u1 ? a1 * rsqrtf((float)u1) : 0.f;
            vbar2[(size_t)(nr + 2) * 32 + d] = u2 ? a2 * rsqrtf((float)u2) : 0.f;
            vbar2[(size_t)(nr + 3) * 32 + d] = u3 ? a3 * rsqrtf((float)u3) : 0.f;
        } else {
            // tail tile (not hit for N=100000)
            for (int r = 0; r < 4; r++) {
                int n = nr + r;
                if (n >= N) break;
                float a = bvbar;
                const float* xb = xs + (size_t)n * 128;
                for (int i4 = 0; i4 < 32; i4++) {
                    float4 w = WTP[i4 * 32 + d];
                    float4 xv = *(const float4*)(xb + i4 * 4);
                    a += xv.x * w.x + xv.y * w.y + xv.z * w.z + xv.w * w.w;
                }
                csum += a;
                unsigned u = deg[n];
                vbar2[(size_t)n * 32 + d] = u ? a * rsqrtf((float)u) : 0.f;
            }
        }
    }

    red[tid] = csum;
    __syncthreads();
    if (tid < 32) {
        float s = red[tid] + red[32 + tid] + red[64 + tid] + red[96 + tid] +
                  red[128 + tid] + red[160 + tid] + red[192 + tid] + red[224 + tid];
        atomicAdd(&g_csum[tid], s);
    }
}

// ---------------------------------------------------------------------------
// K3: single-block scan of padded (16-edge-aligned) sub-segment sizes
//     -> base[k], gcur[k] for k = bucket*8 + writer
// ---------------------------------------------------------------------------
__global__ __launch_bounds__(256) void scan_kernel(const unsigned* __restrict__ bcnt8,
                                                   int K, unsigned* __restrict__ base,
                                                   unsigned* __restrict__ gcur) {
    __shared__ unsigned s[256];
    const int tid = threadIdx.x;
    const int per = (K + 255) / 256;
    const int t0 = tid * per;
    unsigned local = 0;
    for (int j = 0; j < per; j++) {
        int k = t0 + j;
        if (k < K) local += (bcnt8[k] + 15u) & ~15u;
    }
    s[tid] = local;
    __syncthreads();
    for (int off = 1; off < 256; off <<= 1) {
        unsigned v = (tid >= off) ? s[tid - off] : 0u;
        __syncthreads();
        s[tid] += v;
        __syncthreads();
    }
    unsigned run = s[tid] - local;
    for (int j = 0; j < per; j++) {
        int k = t0 + j;
        if (k < K) {
            unsigned c = bcnt8[k];
            base[k] = run;
            gcur[k] = run;
            run += (c + 15u) & ~15u;
        }
    }
}

// ---------------------------------------------------------------------------
// K4: XCD-local ticketed fill. Same chunking as hist -> same writer&7 per edge.
// Each (bucket, writer) sub-region is 64B-aligned and written by one XCD only.
// ---------------------------------------------------------------------------
__global__ __launch_bounds__(256) void fill_kernel(const int* __restrict__ ei, int E,
                                                   int chunk, unsigned* __restrict__ gcur,
                                                   unsigned* __restrict__ sorted) {
    const int e0 = blockIdx.x * chunk;
    const int e1 = min(E, e0 + chunk);
    const int x = blockIdx.x & 7;
    for (int e = e0 + threadIdx.x; e < e1; e += 256) {
        int row = ei[e];
        int col = ei[E + e];
        unsigned k = (unsigned)(col >> 7) * 8u + (unsigned)x;
        unsigned pos = atomicAdd(&gcur[k], 1u);
        sorted[pos] = (unsigned)row | ((unsigned)(col & 127) << 20);
    }
}

// ---------------------------------------------------------------------------
// K5: fused per-bucket gather. Block b owns cols [b*128, b*128+128):
// stream the 8 sub-segments, accumulate into LDS acc[128][32] via ds f32
// atomics, then write out = cst + rsqrt(deg)*acc.
// ---------------------------------------------------------------------------
__global__ __launch_bounds__(256) void gather_kernel(
    const unsigned* __restrict__ base, const unsigned* __restrict__ gcur,
    const unsigned* __restrict__ sorted, const float* __restrict__ vbar2,
    const float* __restrict__ g_csum, const unsigned* __restrict__ deg,
    float* __restrict__ out, int N, float invN)
{
    __shared__ float acc[128 * 32];
    const int tid = threadIdx.x;
    const int g = tid >> 5, d = tid & 31;
    const int b = blockIdx.x;

    for (int i = tid; i < 128 * 32; i += 256) acc[i] = 0.f;
    const float cstv = g_csum[d] * invN;
    __syncthreads();

#pragma unroll
    for (int x = 0; x < 8; x++) {
        const unsigned k = (unsigned)b * 8u + (unsigned)x;
        const unsigned s = base[k];
        const unsigned e = gcur[k];
        for (unsigned p0 = s + (unsigned)g * 32u; p0 < e; p0 += 256u) {
            const int cnt = (int)min(32u, e - p0);
            unsigned pe = p0 + (unsigned)d;
            if (pe >= e) pe = e - 1;
            int m = (int)sorted[pe];
            if (cnt == 32) {
#pragma unroll
                for (int j = 0; j < 32; j++) {
                    int r = __shfl(m, j, 32);
                    int row = r & 0xFFFFF;
                    int cl = (unsigned)r >> 20;
                    atomicAdd(&acc[cl * 32 + d], vbar2[(size_t)row * 32 + d]);
                }
            } else {
                for (int j = 0; j < cnt; j++) {
                    int r = __shfl(m, j, 32);
                    int row = r & 0xFFFFF;
                    int cl = (unsigned)r >> 20;
                    atomicAdd(&acc[cl * 32 + d], vbar2[(size_t)row * 32 + d]);
                }
            }
        }
    }
    __syncthreads();

#pragma unroll
    for (int it = 0; it < 16; it++) {
        int cl = it * 8 + g;
        int n = b * 128 + cl;
        if (n < N) {
            unsigned u = deg[n];
            float sn = u ? rsqrtf((float)u) : 0.f;
            out[(size_t)n * 32 + d] = cstv + sn * acc[cl * 32 + d];
        }
    }
}

// ---------------------------------------------------------------------------
extern "C" void kernel_launch(void* const* d_in, const int* in_sizes, int n_in,
                              void* d_out, int out_size, void* d_ws, size_t ws_size,
                              hipStream_t stream) {
    const float* xs = (const float*)d_in[1];
    const int*   ei = (const int*)d_in[2];
    const float* Wv = (const float*)d_in[7];
    const float* bv = (const float*)d_in[8];
    float* out = (float*)d_out;

    const int N = in_sizes[0] / 128;
    const int E = in_sizes[2] / 2;
    const int NBUK = (N + 127) >> 7;        // 782 buckets of 128 cols
    const int K = NBUK * 8;                 // sub-segments (bucket x writer)
    const int chunk = (E + GRID_EDGE - 1) / GRID_EDGE;

    char* ws = (char*)d_ws;
    size_t o = 0;
    float*    vbar2  = (float*)(ws + o);    o += (size_t)N * 32 * 4;
    unsigned* deg    = (unsigned*)(ws + o); o += (size_t)N * 4;
    float*    g_csum = (float*)(ws + o);    o += 32 * 4;
    unsigned* bcnt8  = (unsigned*)(ws + o); o += (size_t)K * 4;
    unsigned* base   = (unsigned*)(ws + o); o += (size_t)K * 4;
    unsigned* gcur   = (unsigned*)(ws + o); o += (size_t)K * 4;
    float4*   WTP    = (float4*)(ws + o);   o += 4096 * 4;
    unsigned* sorted = (unsigned*)(ws + o); o += ((size_t)E + (size_t)K * 16) * 4;

    // zero deg + g_csum + bcnt8 (contiguous)
    hipMemsetAsync(deg, 0, ((size_t)N + 32 + (size_t)K) * 4, stream);

    wt_kernel<<<4, 256, 0, stream>>>(Wv, WTP);
    hist_kernel<<<GRID_EDGE, 256, 0, stream>>>(ei, E, chunk, deg, bcnt8);
    vbar_kernel<<<1024, 256, 0, stream>>>(xs, WTP, bv, deg, vbar2, g_csum, N);
    scan_kernel<<<1, 256, 0, stream>>>(bcnt8, K, base, gcur);
    fill_kernel<<<GRID_EDGE, 256, 0, stream>>>(ei, E, chunk, gcur, sorted);
    gather_kernel<<<NBUK, 256, 0, stream>>>(base, gcur, sorted, vbar2, g_csum,
                                            deg, out, N, 1.0f / (float)N);
}

// Round 6
// 379.764 us; speedup vs baseline: 1.8286x; 1.8286x over previous
//
#include <hip/hip_runtime.h>
#include <hip/hip_bf16.h>

// N = 100000, E = 1600000, IN = 128, H = 4, D = 32
//
// Math (validated rounds 1-5, absmax 9.8e-4 vs threshold 8.2e-3):
//   vbar[n]  = xs[n] @ WT^T + bvbar          (WT[d][i] = 0.25*sum_h Wv[i][32h+d])
//   vbar2[n] = vbar[n] * (deg[n]? rsqrt(deg[n]) : 0)
//   cst[d]   = mean_n vbar[n,d]
//   out[n,d] = cst[d] + (deg[n]? rsqrt(deg[n]):0) * sum_{e:col=n} vbar2[row_e, d]
//
// Round-6 structure:
//   hist (XCD-sharded deg8 + XCD-major bcnt8) -> reduce_deg -> vbar (LDS-free)
//   scanA/B/C -> rowptr ; scanK -> sub-segment bases
//   fill: XCD-local bucket-grouped meta (row | (col&127)<<20)
//   sort: per-bucket LDS-cursor counting sort -> fully col-sorted sorted2
//   gather: per-node (32 lanes), register accumulate.

#define GRID_EDGE 1024

// ---------------------------------------------------------------------------
// K0: WTP[i4*32+d] = {wt(4*i4+j, d)}_{j=0..3}, wt(i,d)=0.25*sum_h Wv[i*128+32h+d]
// ---------------------------------------------------------------------------
__global__ __launch_bounds__(256) void wt_kernel(const float* __restrict__ Wv,
                                                 float4* __restrict__ WTP) {
    int idx = blockIdx.x * 256 + threadIdx.x;
    if (idx < 1024) {
        int i4 = idx >> 5, d = idx & 31;
        float c[4];
#pragma unroll
        for (int j = 0; j < 4; j++) {
            int i = i4 * 4 + j;
            c[j] = 0.25f * (Wv[i * 128 + d] + Wv[i * 128 + 32 + d] +
                            Wv[i * 128 + 64 + d] + Wv[i * 128 + 96 + d]);
        }
        WTP[idx] = make_float4(c[0], c[1], c[2], c[3]);
    }
}

// ---------------------------------------------------------------------------
// K1: histogram. deg8[x*N+col]++ and bcnt8[x*NBUK+bucket]++ with x=blockIdx&7
// (XCD-private regions -> atomic lines stay in one L2).
// ---------------------------------------------------------------------------
__global__ __launch_bounds__(256) void hist_kernel(const int* __restrict__ ei, int E,
                                                   int chunk, int N, int NBUK,
                                                   unsigned* __restrict__ deg8,
                                                   unsigned* __restrict__ bcnt8) {
    const int e0 = blockIdx.x * chunk;
    const int e1 = min(E, e0 + chunk);
    const int x = blockIdx.x & 7;
    unsigned* degx = deg8 + (size_t)x * N;
    unsigned* bcx  = bcnt8 + (size_t)x * NBUK;
    for (int e = e0 + threadIdx.x; e < e1; e += 256) {
        int col = ei[E + e];
        atomicAdd(&degx[col], 1u);
        atomicAdd(&bcx[col >> 7], 1u);
    }
}

// ---------------------------------------------------------------------------
// K1b: deg[n] = sum_x deg8[x*N+n]
// ---------------------------------------------------------------------------
__global__ __launch_bounds__(256) void reduce_deg_kernel(const unsigned* __restrict__ deg8,
                                                         unsigned* __restrict__ deg, int N) {
    int n = blockIdx.x * 256 + threadIdx.x;
    if (n < N) {
        unsigned s = 0;
#pragma unroll
        for (int x = 0; x < 8; x++) s += deg8[(size_t)x * N + n];
        deg[n] = s;
    }
}

// ---------------------------------------------------------------------------
// K2: vbar2 = (xs @ WT^T + bvbar) * rsqrt(deg)  +  column-sum partials (cst).
// LDS-free: per 32-lane group, 4 nodes; x broadcast float4 loads, WTP coalesced.
// ---------------------------------------------------------------------------
__global__ __launch_bounds__(256) void vbar_kernel(
    const float* __restrict__ xs, const float4* __restrict__ WTP,
    const float* __restrict__ bv, const unsigned* __restrict__ deg,
    float* __restrict__ vbar2, float* __restrict__ g_csum, int N)
{
    __shared__ float red[256];
    const int tid = threadIdx.x;
    const int wave = tid >> 6, lane = tid & 63;
    const int g = lane >> 5, d = lane & 31;
    const float bvbar = 0.25f * (bv[d] + bv[32 + d] + bv[64 + d] + bv[96 + d]);
    float csum = 0.f;

    const int ntiles = (N + 7) >> 3;
    const int wglob = blockIdx.x * 4 + wave;
    const int nwaves = gridDim.x * 4;

    for (int t = wglob; t < ntiles; t += nwaves) {
        const int nr = t * 8 + g * 4;
        float a0 = bvbar, a1 = bvbar, a2 = bvbar, a3 = bvbar;
        if (nr + 3 < N) {
            const float* xb = xs + (size_t)nr * 128;
#pragma unroll 8
            for (int i4 = 0; i4 < 32; i4++) {
                float4 w = WTP[i4 * 32 + d];
                float4 x0 = *(const float4*)(xb + i4 * 4);
                float4 x1 = *(const float4*)(xb + 128 + i4 * 4);
                float4 x2 = *(const float4*)(xb + 256 + i4 * 4);
                float4 x3 = *(const float4*)(xb + 384 + i4 * 4);
                a0 += x0.x * w.x + x0.y * w.y + x0.z * w.z + x0.w * w.w;
                a1 += x1.x * w.x + x1.y * w.y + x1.z * w.z + x1.w * w.w;
                a2 += x2.x * w.x + x2.y * w.y + x2.z * w.z + x2.w * w.w;
                a3 += x3.x * w.x + x3.y * w.y + x3.z * w.z + x3.w * w.w;
            }
            csum += a0 + a1 + a2 + a3;
            unsigned u0 = deg[nr + 0], u1 = deg[nr + 1], u2 = deg[nr + 2], u3 = deg[nr + 3];
            vbar2[(size_t)(nr + 0) * 32 + d] = u0 ? a0 * rsqrtf((float)u0) : 0.f;
            vbar2[(size_t)(nr + 1) * 32 + d] = u1 ? a1 * rsqrtf((float)u1) : 0.f;
            vbar2[(size_t)(nr + 2) * 32 + d] = u2 ? a2 * rsqrtf((float)u2) : 0.f;
            vbar2[(size_t)(nr + 3) * 32 + d] = u3 ? a3 * rsqrtf((float)u3) : 0.f;
        } else {
            for (int r = 0; r < 4; r++) {
                int n = nr + r;
                if (n >= N) break;
                float a = bvbar;
                const float* xb = xs + (size_t)n * 128;
                for (int i4 = 0; i4 < 32; i4++) {
                    float4 w = WTP[i4 * 32 + d];
                    float4 xv = *(const float4*)(xb + i4 * 4);
                    a += xv.x * w.x + xv.y * w.y + xv.z * w.z + xv.w * w.w;
                }
                csum += a;
                unsigned u = deg[n];
                vbar2[(size_t)n * 32 + d] = u ? a * rsqrtf((float)u) : 0.f;
            }
        }
    }

    red[tid] = csum;
    __syncthreads();
    if (tid < 32) {
        float s = red[tid] + red[32 + tid] + red[64 + tid] + red[96 + tid] +
                  red[128 + tid] + red[160 + tid] + red[192 + tid] + red[224 + tid];
        atomicAdd(&g_csum[tid], s);
    }
}

// ---------------------------------------------------------------------------
// K3a: per-1024-chunk degree sums
// ---------------------------------------------------------------------------
__global__ __launch_bounds__(256) void scanA_kernel(const unsigned* __restrict__ deg,
                                                    int N, unsigned* __restrict__ bsum) {
    __shared__ unsigned s[256];
    const int tid = threadIdx.x;
    const int i0 = blockIdx.x * 1024 + tid * 4;
    unsigned t = 0;
#pragma unroll
    for (int j = 0; j < 4; j++) { int i = i0 + j; if (i < N) t += deg[i]; }
    s[tid] = t; __syncthreads();
    for (int off = 128; off > 0; off >>= 1) {
        if (tid < off) s[tid] += s[tid + off];
        __syncthreads();
    }
    if (tid == 0) bsum[blockIdx.x] = s[0];
}

// ---------------------------------------------------------------------------
// K3b: exclusive scan of chunk sums (<=128)
// ---------------------------------------------------------------------------
__global__ __launch_bounds__(128) void scanB_kernel(const unsigned* __restrict__ bsum,
                                                    unsigned* __restrict__ boff, int nb) {
    __shared__ unsigned s[128];
    const int tid = threadIdx.x;
    unsigned v = (tid < nb) ? bsum[tid] : 0u;
    s[tid] = v; __syncthreads();
    for (int off = 1; off < 128; off <<= 1) {
        unsigned t = (tid >= off) ? s[tid - off] : 0u;
        __syncthreads();
        s[tid] += t;
        __syncthreads();
    }
    if (tid < nb) boff[tid] = s[tid] - v;
}

// ---------------------------------------------------------------------------
// K3c: full exclusive scan -> rowptr[N+1]
// ---------------------------------------------------------------------------
__global__ __launch_bounds__(256) void scanC_kernel(
    const unsigned* __restrict__ deg, const unsigned* __restrict__ boff,
    int N, int E, unsigned* __restrict__ rowptr)
{
    __shared__ unsigned s[256];
    const int tid = threadIdx.x;
    const int i0 = blockIdx.x * 1024 + tid * 4;
    unsigned d0 = 0, d1 = 0, d2 = 0, d3 = 0;
    if (i0 + 0 < N) d0 = deg[i0 + 0];
    if (i0 + 1 < N) d1 = deg[i0 + 1];
    if (i0 + 2 < N) d2 = deg[i0 + 2];
    if (i0 + 3 < N) d3 = deg[i0 + 3];
    const unsigned tsum = d0 + d1 + d2 + d3;
    s[tid] = tsum; __syncthreads();
    for (int off = 1; off < 256; off <<= 1) {
        unsigned t = (tid >= off) ? s[tid - off] : 0u;
        __syncthreads();
        s[tid] += t;
        __syncthreads();
    }
    unsigned base = boff[blockIdx.x] + s[tid] - tsum;
    unsigned p0 = base, p1 = base + d0, p2 = p1 + d1, p3 = p2 + d2;
    if (i0 + 0 < N) rowptr[i0 + 0] = p0;
    if (i0 + 1 < N) rowptr[i0 + 1] = p1;
    if (i0 + 2 < N) rowptr[i0 + 2] = p2;
    if (i0 + 3 < N) rowptr[i0 + 3] = p3;
    if (blockIdx.x == 0 && tid == 0) rowptr[N] = (unsigned)E;
}

// ---------------------------------------------------------------------------
// K3d: scan of padded (16-aligned) sub-segment sizes, k = x*NBUK + bucket
// ---------------------------------------------------------------------------
__global__ __launch_bounds__(256) void scanK_kernel(const unsigned* __restrict__ bcnt8,
                                                    int K, unsigned* __restrict__ base,
                                                    unsigned* __restrict__ gcur) {
    __shared__ unsigned s[256];
    const int tid = threadIdx.x;
    const int per = (K + 255) / 256;
    const int t0 = tid * per;
    unsigned local = 0;
    for (int j = 0; j < per; j++) {
        int k = t0 + j;
        if (k < K) local += (bcnt8[k] + 15u) & ~15u;
    }
    s[tid] = local;
    __syncthreads();
    for (int off = 1; off < 256; off <<= 1) {
        unsigned v = (tid >= off) ? s[tid - off] : 0u;
        __syncthreads();
        s[tid] += v;
        __syncthreads();
    }
    unsigned run = s[tid] - local;
    for (int j = 0; j < per; j++) {
        int k = t0 + j;
        if (k < K) {
            unsigned c = bcnt8[k];
            base[k] = run;
            gcur[k] = run;
            run += (c + 15u) & ~15u;
        }
    }
}

// ---------------------------------------------------------------------------
// K4: XCD-local ticketed fill into bucket-grouped meta array.
// dest sub-segment k = x*NBUK + (col>>7); meta = row | (col&127)<<20.
// ---------------------------------------------------------------------------
__global__ __launch_bounds__(256) void fill_kernel(const int* __restrict__ ei, int E,
                                                   int chunk, int NBUK,
                                                   unsigned* __restrict__ gcur,
                                                   unsigned* __restrict__ sorted) {
    const int e0 = blockIdx.x * chunk;
    const int e1 = min(E, e0 + chunk);
    const int x = blockIdx.x & 7;
    unsigned* gc = gcur + (size_t)x * NBUK;
    for (int e = e0 + threadIdx.x; e < e1; e += 256) {
        int row = ei[e];
        int col = ei[E + e];
        unsigned pos = atomicAdd(&gc[col >> 7], 1u);
        sorted[pos] = (unsigned)row | ((unsigned)(col & 127) << 20);
    }
}

// ---------------------------------------------------------------------------
// K5: per-bucket counting sort: bucket-grouped meta -> fully col-sorted rows.
// Block b handles cols [b*128, b*128+128); LDS cursors seeded from rowptr;
// all writes land inside the bucket's private contiguous range.
// ---------------------------------------------------------------------------
__global__ __launch_bounds__(256) void sort_kernel(
    const unsigned* __restrict__ base, const unsigned* __restrict__ gcur,
    const unsigned* __restrict__ sorted, const unsigned* __restrict__ rowptr,
    unsigned* __restrict__ sorted2, int N, int NBUK)
{
    __shared__ unsigned cur[128];
    const int tid = threadIdx.x;
    const int b = blockIdx.x;
    if (tid < 128) {
        int idx = b * 128 + tid;
        cur[tid] = rowptr[idx <= N ? idx : N];
    }
    __syncthreads();
#pragma unroll
    for (int x = 0; x < 8; x++) {
        const int k = x * NBUK + b;
        const unsigned s = base[k];
        const unsigned e = gcur[k];
        for (unsigned p = s + (unsigned)tid; p < e; p += 256u) {
            unsigned m = sorted[p];
            unsigned row = m & 0xFFFFFu;
            unsigned cl = m >> 20;
            unsigned pos = atomicAdd(&cur[cl], 1u);
            sorted2[pos] = row;
        }
    }
}

// ---------------------------------------------------------------------------
// K6: per-node gather: out[n,d] = cst[d] + rsqrt(deg[n]) * sum_p vbar2[row_p, d]
// ---------------------------------------------------------------------------
__global__ __launch_bounds__(256) void gather_kernel(
    const unsigned* __restrict__ rowptr, const unsigned* __restrict__ sorted2,
    const float* __restrict__ vbar2, const float* __restrict__ g_csum,
    const unsigned* __restrict__ deg, float* __restrict__ out, int N, float invN)
{
    const int tid = threadIdx.x;
    const int n = blockIdx.x * 8 + (tid >> 5);
    const int d = tid & 31;
    if (n >= N) return;
    const unsigned s = rowptr[n];
    const unsigned e = rowptr[n + 1];
    float acc = 0.f;
    for (unsigned p0 = s; p0 < e; p0 += 32) {
        const int cnt = (int)min(32u, e - p0);
        unsigned pe = p0 + (unsigned)d;
        if (pe >= e) pe = e - 1;
        int m = (int)sorted2[pe];
        int j = 0;
        for (; j + 3 < cnt; j += 4) {
            int r0 = __shfl(m, j + 0, 32);
            int r1 = __shfl(m, j + 1, 32);
            int r2 = __shfl(m, j + 2, 32);
            int r3 = __shfl(m, j + 3, 32);
            float f0 = vbar2[(size_t)r0 * 32 + d];
            float f1 = vbar2[(size_t)r1 * 32 + d];
            float f2 = vbar2[(size_t)r2 * 32 + d];
            float f3 = vbar2[(size_t)r3 * 32 + d];
            acc += f0 + f1 + f2 + f3;
        }
        for (; j < cnt; j++) {
            int r0 = __shfl(m, j, 32);
            acc += vbar2[(size_t)r0 * 32 + d];
        }
    }
    unsigned u = deg[n];
    float sn = u ? rsqrtf((float)u) : 0.f;
    out[(size_t)n * 32 + d] = g_csum[d] * invN + sn * acc;
}

// ---------------------------------------------------------------------------
extern "C" void kernel_launch(void* const* d_in, const int* in_sizes, int n_in,
                              void* d_out, int out_size, void* d_ws, size_t ws_size,
                              hipStream_t stream) {
    const float* xs = (const float*)d_in[1];
    const int*   ei = (const int*)d_in[2];
    const float* Wv = (const float*)d_in[7];
    const float* bv = (const float*)d_in[8];
    float* out = (float*)d_out;

    const int N = in_sizes[0] / 128;
    const int E = in_sizes[2] / 2;
    const int NBUK = (N + 127) >> 7;
    const int K = NBUK * 8;
    const int chunk = (E + GRID_EDGE - 1) / GRID_EDGE;

    char* ws = (char*)d_ws;
    size_t o = 0;
    float*    vbar2   = (float*)(ws + o);    o += (size_t)N * 32 * 4;
    // --- contiguous zeroed region: deg, g_csum, bcnt8, deg8 ---
    unsigned* deg     = (unsigned*)(ws + o); o += (size_t)N * 4;
    float*    g_csum  = (float*)(ws + o);    o += 32 * 4;
    unsigned* bcnt8   = (unsigned*)(ws + o); o += (size_t)K * 4;
    unsigned* deg8    = (unsigned*)(ws + o); o += (size_t)N * 8 * 4;
    const size_t zbytes = (size_t)(N + 32 + K + 8 * N) * 4;
    // ----------------------------------------------------------
    unsigned* rowptr  = (unsigned*)(ws + o); o += (size_t)(N + 1) * 4;
    unsigned* bsum    = (unsigned*)(ws + o); o += 128 * 4;
    unsigned* boff    = (unsigned*)(ws + o); o += 128 * 4;
    unsigned* base    = (unsigned*)(ws + o); o += (size_t)K * 4;
    unsigned* gcur    = (unsigned*)(ws + o); o += (size_t)K * 4;
    float4*   WTP     = (float4*)(ws + o);   o += 4096 * 4;
    unsigned* sorted  = (unsigned*)(ws + o); o += ((size_t)E + (size_t)K * 16) * 4;
    unsigned* sorted2 = (unsigned*)(ws + o); o += (size_t)E * 4;

    hipMemsetAsync(deg, 0, zbytes, stream);

    wt_kernel<<<4, 256, 0, stream>>>(Wv, WTP);
    hist_kernel<<<GRID_EDGE, 256, 0, stream>>>(ei, E, chunk, N, NBUK, deg8, bcnt8);
    reduce_deg_kernel<<<(N + 255) / 256, 256, 0, stream>>>(deg8, deg, N);
    vbar_kernel<<<1024, 256, 0, stream>>>(xs, WTP, bv, deg, vbar2, g_csum, N);
    scanA_kernel<<<(N + 1023) / 1024, 256, 0, stream>>>(deg, N, bsum);
    scanB_kernel<<<1, 128, 0, stream>>>(bsum, boff, (N + 1023) / 1024);
    scanC_kernel<<<(N + 1023) / 1024, 256, 0, stream>>>(deg, boff, N, E, rowptr);
    scanK_kernel<<<1, 256, 0, stream>>>(bcnt8, K, base, gcur);
    fill_kernel<<<GRID_EDGE, 256, 0, stream>>>(ei, E, chunk, NBUK, gcur, sorted);
    sort_kernel<<<NBUK, 256, 0, stream>>>(base, gcur, sorted, rowptr, sorted2, N, NBUK);
    gather_kernel<<<(N + 7) / 8, 256, 0, stream>>>(rowptr, sorted2, vbar2, g_csum,
                                                   deg, out, N, 1.0f / (float)N);
}

// Round 7
// 164.726 us; speedup vs baseline: 4.2158x; 2.3054x over previous
//
#include <hip/hip_runtime.h>
#include <hip/hip_bf16.h>

// N = 100000, E = 1600000, IN = 128, H = 4, D = 32
//
// Math (validated rounds 1-6, absmax 9.8e-4 vs threshold 8.2e-3):
//   vbar[n]  = xs[n] @ WT^T + bvbar          (WT[d][i] = 0.25*sum_h Wv[i][32h+d])
//   vbar2[n] = vbar[n] * (deg[n]? rsqrt(deg[n]) : 0)
//   cst[d]   = mean_n vbar[n,d]
//   out[n,d] = cst[d] + (deg[n]? rsqrt(deg[n]):0) * sum_{e:col=n} vbar2[row_e, d]
//
// Round-7: counting sort with per-block private cursors -> ZERO global atomics
// on the edge path (device-scope atomics execute at the coherent point at
// ~25G/s; round-6 hist's 3.2M atomics = 129us).
//   hist:   per-block LDS bucket histogram -> bcnt_pb[block][NBUK] (coalesced)
//   scanPB: per-bucket exclusive scan over blocks in XCD-major order
//   bucketScan: bucket bases
//   fill:   LDS cursors seeded per-block -> bucket-grouped meta (row|(col&127)<<20)
//   sort:   per-bucket LDS col-histogram -> deg, rowptr, col-sorted sorted2
//   vbar:   LDS-free GEMM, folds rsqrt(deg); gather: per-node 32-lane.

#define GRID_EDGE 1024
#define MAXBUK 1024   // supports N <= 131072

// ---------------------------------------------------------------------------
// K0: WTP[i4*32+d] = {wt(4*i4+j, d)}_{j=0..3}, wt(i,d)=0.25*sum_h Wv[i*128+32h+d]
// ---------------------------------------------------------------------------
__global__ __launch_bounds__(256) void wt_kernel(const float* __restrict__ Wv,
                                                 float4* __restrict__ WTP) {
    int idx = blockIdx.x * 256 + threadIdx.x;
    if (idx < 1024) {
        int i4 = idx >> 5, d = idx & 31;
        float c[4];
#pragma unroll
        for (int j = 0; j < 4; j++) {
            int i = i4 * 4 + j;
            c[j] = 0.25f * (Wv[i * 128 + d] + Wv[i * 128 + 32 + d] +
                            Wv[i * 128 + 64 + d] + Wv[i * 128 + 96 + d]);
        }
        WTP[idx] = make_float4(c[0], c[1], c[2], c[3]);
    }
}

// ---------------------------------------------------------------------------
// K1: per-block LDS bucket histogram -> bcnt_pb[block][NBUK] (coalesced store)
// ---------------------------------------------------------------------------
__global__ __launch_bounds__(256) void hist_kernel(const int* __restrict__ ei, int E,
                                                   int chunk, int NBUK,
                                                   unsigned* __restrict__ bcnt_pb) {
    __shared__ unsigned h[MAXBUK];
    const int tid = threadIdx.x;
    for (int k = tid; k < NBUK; k += 256) h[k] = 0u;
    __syncthreads();
    const int e0 = blockIdx.x * chunk;
    const int e1 = min(E, e0 + chunk);
    for (int e = e0 + tid; e < e1; e += 256)
        atomicAdd(&h[ei[E + e] >> 7], 1u);
    __syncthreads();
    unsigned* dst = bcnt_pb + (size_t)blockIdx.x * NBUK;
    for (int k = tid; k < NBUK; k += 256) dst[k] = h[k];
}

// ---------------------------------------------------------------------------
// K2: per-bucket exclusive scan over the 1024 blocks in XCD-major logical
// order i: physical block p(i) = (i&127)*8 + (i>>7). Writes
// partial_pb[bucket][i] (contiguous) and colsum[bucket].
// ---------------------------------------------------------------------------
__global__ __launch_bounds__(256) void scanPB_kernel(const unsigned* __restrict__ bcnt_pb,
                                                     int NBUK,
                                                     unsigned* __restrict__ partial_pb,
                                                     unsigned* __restrict__ colsum) {
    __shared__ unsigned s[256];
    const int b = blockIdx.x;
    const int tid = threadIdx.x;
    unsigned v[4], local = 0;
#pragma unroll
    for (int j = 0; j < 4; j++) {
        int i = tid * 4 + j;
        int p = (i & 127) * 8 + (i >> 7);
        v[j] = bcnt_pb[(size_t)p * NBUK + b];
        local += v[j];
    }
    s[tid] = local;
    __syncthreads();
    for (int off = 1; off < 256; off <<= 1) {
        unsigned t = (tid >= off) ? s[tid - off] : 0u;
        __syncthreads();
        s[tid] += t;
        __syncthreads();
    }
    unsigned run = s[tid] - local;
    unsigned* dst = partial_pb + (size_t)b * 1024;
#pragma unroll
    for (int j = 0; j < 4; j++) {
        dst[tid * 4 + j] = run;
        run += v[j];
    }
    if (tid == 255) colsum[b] = run;
}

// ---------------------------------------------------------------------------
// K3: exclusive scan of colsum -> bucketBase[NBUK+1]
// ---------------------------------------------------------------------------
__global__ __launch_bounds__(256) void bucketScan_kernel(const unsigned* __restrict__ colsum,
                                                         int NBUK, int E,
                                                         unsigned* __restrict__ bucketBase) {
    __shared__ unsigned s[256];
    const int tid = threadIdx.x;
    unsigned v[4], local = 0;
#pragma unroll
    for (int j = 0; j < 4; j++) {
        int i = tid * 4 + j;
        v[j] = (i < NBUK) ? colsum[i] : 0u;
        local += v[j];
    }
    s[tid] = local;
    __syncthreads();
    for (int off = 1; off < 256; off <<= 1) {
        unsigned t = (tid >= off) ? s[tid - off] : 0u;
        __syncthreads();
        s[tid] += t;
        __syncthreads();
    }
    unsigned run = s[tid] - local;
#pragma unroll
    for (int j = 0; j < 4; j++) {
        int i = tid * 4 + j;
        if (i < NBUK) bucketBase[i] = run;
        run += v[j];
    }
    if (tid == 0) bucketBase[NBUK] = (unsigned)E;
}

// ---------------------------------------------------------------------------
// K4: fill with per-block private LDS cursors (no global atomics).
// cur[k] = bucketBase[k] + partial_pb[k][i(p)],  i(p) = (p&7)*128 + (p>>3).
// ---------------------------------------------------------------------------
__global__ __launch_bounds__(256) void fill_kernel(const int* __restrict__ ei, int E,
                                                   int chunk, int NBUK,
                                                   const unsigned* __restrict__ partial_pb,
                                                   const unsigned* __restrict__ bucketBase,
                                                   unsigned* __restrict__ sorted) {
    __shared__ unsigned cur[MAXBUK];
    const int tid = threadIdx.x;
    const int p = blockIdx.x;
    const int i = (p & 7) * 128 + (p >> 3);
    for (int k = tid; k < NBUK; k += 256)
        cur[k] = bucketBase[k] + partial_pb[(size_t)k * 1024 + i];
    __syncthreads();
    const int e0 = p * chunk;
    const int e1 = min(E, e0 + chunk);
    for (int e = e0 + tid; e < e1; e += 256) {
        int row = ei[e];
        int col = ei[E + e];
        unsigned pos = atomicAdd(&cur[col >> 7], 1u);
        sorted[pos] = (unsigned)row | ((unsigned)(col & 127) << 20);
    }
}

// ---------------------------------------------------------------------------
// K5: per-bucket counting sort + deg + rowptr. Block b owns cols
// [b*128, b*128+128); all global writes land in block-private regions.
// ---------------------------------------------------------------------------
__global__ __launch_bounds__(256) void sort_kernel(
    const unsigned* __restrict__ bucketBase, const unsigned* __restrict__ sorted,
    unsigned* __restrict__ deg, unsigned* __restrict__ rowptr,
    unsigned* __restrict__ sorted2, int N)
{
    __shared__ unsigned h[128];
    __shared__ unsigned sc[128];
    __shared__ unsigned cur[128];
    const int tid = threadIdx.x;
    const int b = blockIdx.x;
    if (tid < 128) h[tid] = 0u;
    __syncthreads();
    const unsigned s = bucketBase[b];
    const unsigned e = bucketBase[b + 1];
    for (unsigned p = s + (unsigned)tid; p < e; p += 256u)
        atomicAdd(&h[sorted[p] >> 20], 1u);
    __syncthreads();
    if (tid < 128) sc[tid] = h[tid];
    __syncthreads();
    for (int off = 1; off < 128; off <<= 1) {
        unsigned t = 0;
        if (tid < 128 && tid >= off) t = sc[tid - off];
        __syncthreads();
        if (tid < 128) sc[tid] += t;
        __syncthreads();
    }
    if (tid < 128) {
        unsigned ex = sc[tid] - h[tid];
        cur[tid] = ex;
        int n = b * 128 + tid;
        if (n < N) { deg[n] = h[tid]; rowptr[n] = s + ex; }
    }
    if (b == (int)gridDim.x - 1 && tid == 0) rowptr[N] = e;
    __syncthreads();
    for (unsigned p = s + (unsigned)tid; p < e; p += 256u) {
        unsigned m = sorted[p];
        unsigned pos = atomicAdd(&cur[m >> 20], 1u);
        sorted2[s + pos] = m & 0xFFFFFu;
    }
}

// ---------------------------------------------------------------------------
// K6: vbar2 = (xs @ WT^T + bvbar) * rsqrt(deg)  +  column-sum partials (cst).
// LDS-free: per 32-lane group, 4 nodes; x broadcast float4 loads, WTP coalesced.
// ---------------------------------------------------------------------------
__global__ __launch_bounds__(256) void vbar_kernel(
    const float* __restrict__ xs, const float4* __restrict__ WTP,
    const float* __restrict__ bv, const unsigned* __restrict__ deg,
    float* __restrict__ vbar2, float* __restrict__ g_csum, int N)
{
    __shared__ float red[256];
    const int tid = threadIdx.x;
    const int wave = tid >> 6, lane = tid & 63;
    const int g = lane >> 5, d = lane & 31;
    const float bvbar = 0.25f * (bv[d] + bv[32 + d] + bv[64 + d] + bv[96 + d]);
    float csum = 0.f;

    const int ntiles = (N + 7) >> 3;
    const int wglob = blockIdx.x * 4 + wave;
    const int nwaves = gridDim.x * 4;

    for (int t = wglob; t < ntiles; t += nwaves) {
        const int nr = t * 8 + g * 4;
        float a0 = bvbar, a1 = bvbar, a2 = bvbar, a3 = bvbar;
        if (nr + 3 < N) {
            const float* xb = xs + (size_t)nr * 128;
#pragma unroll 8
            for (int i4 = 0; i4 < 32; i4++) {
                float4 w = WTP[i4 * 32 + d];
                float4 x0 = *(const float4*)(xb + i4 * 4);
                float4 x1 = *(const float4*)(xb + 128 + i4 * 4);
                float4 x2 = *(const float4*)(xb + 256 + i4 * 4);
                float4 x3 = *(const float4*)(xb + 384 + i4 * 4);
                a0 += x0.x * w.x + x0.y * w.y + x0.z * w.z + x0.w * w.w;
                a1 += x1.x * w.x + x1.y * w.y + x1.z * w.z + x1.w * w.w;
                a2 += x2.x * w.x + x2.y * w.y + x2.z * w.z + x2.w * w.w;
                a3 += x3.x * w.x + x3.y * w.y + x3.z * w.z + x3.w * w.w;
            }
            csum += a0 + a1 + a2 + a3;
            unsigned u0 = deg[nr + 0], u1 = deg[nr + 1], u2 = deg[nr + 2], u3 = deg[nr + 3];
            vbar2[(size_t)(nr + 0) * 32 + d] = u0 ? a0 * rsqrtf((float)u0) : 0.f;
            vbar2[(size_t)(nr + 1) * 32 + d] = u1 ? a1 * rsqrtf((float)u1) : 0.f;
            vbar2[(size_t)(nr + 2) * 32 + d] = u2 ? a2 * rsqrtf((float)u2) : 0.f;
            vbar2[(size_t)(nr + 3) * 32 + d] = u3 ? a3 * rsqrtf((float)u3) : 0.f;
        } else {
            for (int r = 0; r < 4; r++) {
                int n = nr + r;
                if (n >= N) break;
                float a = bvbar;
                const float* xb = xs + (size_t)n * 128;
                for (int i4 = 0; i4 < 32; i4++) {
                    float4 w = WTP[i4 * 32 + d];
                    float4 xv = *(const float4*)(xb + i4 * 4);
                    a += xv.x * w.x + xv.y * w.y + xv.z * w.z + xv.w * w.w;
                }
                csum += a;
                unsigned u = deg[n];
                vbar2[(size_t)n * 32 + d] = u ? a * rsqrtf((float)u) : 0.f;
            }
        }
    }

    red[tid] = csum;
    __syncthreads();
    if (tid < 32) {
        float s = red[tid] + red[32 + tid] + red[64 + tid] + red[96 + tid] +
                  red[128 + tid] + red[160 + tid] + red[192 + tid] + red[224 + tid];
        atomicAdd(&g_csum[tid], s);
    }
}

// ---------------------------------------------------------------------------
// K7: per-node gather: out[n,d] = cst[d] + rsqrt(deg[n]) * sum_p vbar2[row_p, d]
// ---------------------------------------------------------------------------
__global__ __launch_bounds__(256) void gather_kernel(
    const unsigned* __restrict__ rowptr, const unsigned* __restrict__ sorted2,
    const float* __restrict__ vbar2, const float* __restrict__ g_csum,
    const unsigned* __restrict__ deg, float* __restrict__ out, int N, float invN)
{
    const int tid = threadIdx.x;
    const int n = blockIdx.x * 8 + (tid >> 5);
    const int d = tid & 31;
    if (n >= N) return;
    const unsigned s = rowptr[n];
    const unsigned e = rowptr[n + 1];
    float acc = 0.f;
    for (unsigned p0 = s; p0 < e; p0 += 32) {
        const int cnt = (int)min(32u, e - p0);
        unsigned pe = p0 + (unsigned)d;
        if (pe >= e) pe = e - 1;
        int m = (int)sorted2[pe];
        int j = 0;
        for (; j + 3 < cnt; j += 4) {
            int r0 = __shfl(m, j + 0, 32);
            int r1 = __shfl(m, j + 1, 32);
            int r2 = __shfl(m, j + 2, 32);
            int r3 = __shfl(m, j + 3, 32);
            float f0 = vbar2[(size_t)r0 * 32 + d];
            float f1 = vbar2[(size_t)r1 * 32 + d];
            float f2 = vbar2[(size_t)r2 * 32 + d];
            float f3 = vbar2[(size_t)r3 * 32 + d];
            acc += f0 + f1 + f2 + f3;
        }
        for (; j < cnt; j++) {
            int r0 = __shfl(m, j, 32);
            acc += vbar2[(size_t)r0 * 32 + d];
        }
    }
    unsigned u = deg[n];
    float sn = u ? rsqrtf((float)u) : 0.f;
    out[(size_t)n * 32 + d] = g_csum[d] * invN + sn * acc;
}

// ---------------------------------------------------------------------------
extern "C" void kernel_launch(void* const* d_in, const int* in_sizes, int n_in,
                              void* d_out, int out_size, void* d_ws, size_t ws_size,
                              hipStream_t stream) {
    const float* xs = (const float*)d_in[1];
    const int*   ei = (const int*)d_in[2];
    const float* Wv = (const float*)d_in[7];
    const float* bv = (const float*)d_in[8];
    float* out = (float*)d_out;

    const int N = in_sizes[0] / 128;
    const int E = in_sizes[2] / 2;
    const int NBUK = (N + 127) >> 7;                 // 782
    const int chunk = (E + GRID_EDGE - 1) / GRID_EDGE;

    char* ws = (char*)d_ws;
    size_t o = 0;
    float*    vbar2      = (float*)(ws + o);    o += (size_t)N * 32 * 4;
    unsigned* deg        = (unsigned*)(ws + o); o += (size_t)N * 4;
    float*    g_csum     = (float*)(ws + o);    o += 32 * 4;
    unsigned* rowptr     = (unsigned*)(ws + o); o += (size_t)(N + 1) * 4;
    unsigned* bcnt_pb    = (unsigned*)(ws + o); o += (size_t)GRID_EDGE * NBUK * 4;
    unsigned* partial_pb = (unsigned*)(ws + o); o += (size_t)NBUK * 1024 * 4;
    unsigned* colsum     = (unsigned*)(ws + o); o += (size_t)NBUK * 4;
    unsigned* bucketBase = (unsigned*)(ws + o); o += (size_t)(NBUK + 1) * 4;
    float4*   WTP        = (float4*)(ws + o);   o += 4096 * 4;
    unsigned* sorted     = (unsigned*)(ws + o); o += (size_t)E * 4;
    unsigned* sorted2    = (unsigned*)(ws + o); o += (size_t)E * 4;

    hipMemsetAsync(g_csum, 0, 32 * 4, stream);

    wt_kernel<<<4, 256, 0, stream>>>(Wv, WTP);
    hist_kernel<<<GRID_EDGE, 256, 0, stream>>>(ei, E, chunk, NBUK, bcnt_pb);
    scanPB_kernel<<<NBUK, 256, 0, stream>>>(bcnt_pb, NBUK, partial_pb, colsum);
    bucketScan_kernel<<<1, 256, 0, stream>>>(colsum, NBUK, E, bucketBase);
    fill_kernel<<<GRID_EDGE, 256, 0, stream>>>(ei, E, chunk, NBUK, partial_pb,
                                               bucketBase, sorted);
    sort_kernel<<<NBUK, 256, 0, stream>>>(bucketBase, sorted, deg, rowptr, sorted2, N);
    vbar_kernel<<<1024, 256, 0, stream>>>(xs, WTP, bv, deg, vbar2, g_csum, N);
    gather_kernel<<<(N + 7) / 8, 256, 0, stream>>>(rowptr, sorted2, vbar2, g_csum,
                                                   deg, out, N, 1.0f / (float)N);
}

// Round 8
// 115.837 us; speedup vs baseline: 5.9950x; 1.4220x over previous
//
#include <hip/hip_runtime.h>
#include <hip/hip_bf16.h>

// N = 100000, E = 1600000, IN = 128, H = 4, D = 32
//
// Math (validated rounds 1-7, absmax 9.8e-4 vs threshold 8.2e-3):
//   vbar[n]  = xs[n] @ WT^T + bvbar          (WT[d][i] = 0.25*sum_h Wv[i][32h+d])
//   vbar2[n] = vbar[n] * (deg[n]? rsqrt(deg[n]) : 0)
//   cst[d]   = mean_n vbar[n,d]
//   out[n,d] = cst[d] + (deg[n]? rsqrt(deg[n]):0) * sum_{e:col=n} vbar2[row_e, d]
//
// Round-8: vbar via MFMA (bf16 in / f32 acc). A-rows stream coalesced from
// global (no broadcast-load latency trap); B pre-packed into per-lane
// fragments with the SAME k-map as A (any hw k-permutation cancels).
// Edge path (zero global atomics) unchanged from round 7.

#define GRID_EDGE 1024
#define MAXBUK 1024   // supports N <= 131072

typedef __attribute__((ext_vector_type(8))) short    short8v;
typedef __attribute__((ext_vector_type(8))) __bf16   bf16x8;
typedef __attribute__((ext_vector_type(4))) float    f32x4;

__device__ __forceinline__ short f2bf(float f) {
    unsigned u = __float_as_uint(f);
    unsigned r = (u + 0x7FFFu + ((u >> 16) & 1u)) >> 16;   // RNE
    return (short)r;
}

// ---------------------------------------------------------------------------
// K0: pack B fragments. WTB[((dt*4+kt)*64+l)*8+j] = bf16(wt(k,d)),
//     k = kt*32 + (l>>4)*8 + j, d = dt*16 + (l&15),
//     wt(i,d) = 0.25*sum_h Wv[i*128+32h+d].  (512 lane-slots x 8 values)
// ---------------------------------------------------------------------------
__global__ __launch_bounds__(256) void wt_kernel(const float* __restrict__ Wv,
                                                 short* __restrict__ WTB) {
    int idx = blockIdx.x * 256 + threadIdx.x;
    if (idx < 512) {
        int l = idx & 63;
        int kt = (idx >> 6) & 3;
        int dt = idx >> 8;
        int d = dt * 16 + (l & 15);
        int kbase = kt * 32 + (l >> 4) * 8;
#pragma unroll
        for (int j = 0; j < 8; j++) {
            int i = kbase + j;
            float w = 0.25f * (Wv[i * 128 + d] + Wv[i * 128 + 32 + d] +
                               Wv[i * 128 + 64 + d] + Wv[i * 128 + 96 + d]);
            WTB[idx * 8 + j] = f2bf(w);
        }
    }
}

// ---------------------------------------------------------------------------
// K1: per-block LDS bucket histogram -> bcnt_pb[block][NBUK] (coalesced store)
// ---------------------------------------------------------------------------
__global__ __launch_bounds__(256) void hist_kernel(const int* __restrict__ ei, int E,
                                                   int chunk, int NBUK,
                                                   unsigned* __restrict__ bcnt_pb) {
    __shared__ unsigned h[MAXBUK];
    const int tid = threadIdx.x;
    for (int k = tid; k < NBUK; k += 256) h[k] = 0u;
    __syncthreads();
    const int e0 = blockIdx.x * chunk;
    const int e1 = min(E, e0 + chunk);
    for (int e = e0 + tid; e < e1; e += 256)
        atomicAdd(&h[ei[E + e] >> 7], 1u);
    __syncthreads();
    unsigned* dst = bcnt_pb + (size_t)blockIdx.x * NBUK;
    for (int k = tid; k < NBUK; k += 256) dst[k] = h[k];
}

// ---------------------------------------------------------------------------
// K2: per-bucket exclusive scan over the 1024 blocks in XCD-major logical
// order i: physical block p(i) = (i&127)*8 + (i>>7).
// ---------------------------------------------------------------------------
__global__ __launch_bounds__(256) void scanPB_kernel(const unsigned* __restrict__ bcnt_pb,
                                                     int NBUK,
                                                     unsigned* __restrict__ partial_pb,
                                                     unsigned* __restrict__ colsum) {
    __shared__ unsigned s[256];
    const int b = blockIdx.x;
    const int tid = threadIdx.x;
    unsigned v[4], local = 0;
#pragma unroll
    for (int j = 0; j < 4; j++) {
        int i = tid * 4 + j;
        int p = (i & 127) * 8 + (i >> 7);
        v[j] = bcnt_pb[(size_t)p * NBUK + b];
        local += v[j];
    }
    s[tid] = local;
    __syncthreads();
    for (int off = 1; off < 256; off <<= 1) {
        unsigned t = (tid >= off) ? s[tid - off] : 0u;
        __syncthreads();
        s[tid] += t;
        __syncthreads();
    }
    unsigned run = s[tid] - local;
    unsigned* dst = partial_pb + (size_t)b * 1024;
#pragma unroll
    for (int j = 0; j < 4; j++) {
        dst[tid * 4 + j] = run;
        run += v[j];
    }
    if (tid == 255) colsum[b] = run;
}

// ---------------------------------------------------------------------------
// K3: exclusive scan of colsum -> bucketBase[NBUK+1]
// ---------------------------------------------------------------------------
__global__ __launch_bounds__(256) void bucketScan_kernel(const unsigned* __restrict__ colsum,
                                                         int NBUK, int E,
                                                         unsigned* __restrict__ bucketBase) {
    __shared__ unsigned s[256];
    const int tid = threadIdx.x;
    unsigned v[4], local = 0;
#pragma unroll
    for (int j = 0; j < 4; j++) {
        int i = tid * 4 + j;
        v[j] = (i < NBUK) ? colsum[i] : 0u;
        local += v[j];
    }
    s[tid] = local;
    __syncthreads();
    for (int off = 1; off < 256; off <<= 1) {
        unsigned t = (tid >= off) ? s[tid - off] : 0u;
        __syncthreads();
        s[tid] += t;
        __syncthreads();
    }
    unsigned run = s[tid] - local;
#pragma unroll
    for (int j = 0; j < 4; j++) {
        int i = tid * 4 + j;
        if (i < NBUK) bucketBase[i] = run;
        run += v[j];
    }
    if (tid == 0) bucketBase[NBUK] = (unsigned)E;
}

// ---------------------------------------------------------------------------
// K4: fill with per-block private LDS cursors (no global atomics).
// ---------------------------------------------------------------------------
__global__ __launch_bounds__(256) void fill_kernel(const int* __restrict__ ei, int E,
                                                   int chunk, int NBUK,
                                                   const unsigned* __restrict__ partial_pb,
                                                   const unsigned* __restrict__ bucketBase,
                                                   unsigned* __restrict__ sorted) {
    __shared__ unsigned cur[MAXBUK];
    const int tid = threadIdx.x;
    const int p = blockIdx.x;
    const int i = (p & 7) * 128 + (p >> 3);
    for (int k = tid; k < NBUK; k += 256)
        cur[k] = bucketBase[k] + partial_pb[(size_t)k * 1024 + i];
    __syncthreads();
    const int e0 = p * chunk;
    const int e1 = min(E, e0 + chunk);
    for (int e = e0 + tid; e < e1; e += 256) {
        int row = ei[e];
        int col = ei[E + e];
        unsigned pos = atomicAdd(&cur[col >> 7], 1u);
        sorted[pos] = (unsigned)row | ((unsigned)(col & 127) << 20);
    }
}

// ---------------------------------------------------------------------------
// K5: per-bucket counting sort + rsd + rowptr.
// ---------------------------------------------------------------------------
__global__ __launch_bounds__(256) void sort_kernel(
    const unsigned* __restrict__ bucketBase, const unsigned* __restrict__ sorted,
    float* __restrict__ rsd, unsigned* __restrict__ rowptr,
    unsigned* __restrict__ sorted2, int N)
{
    __shared__ unsigned h[128];
    __shared__ unsigned sc[128];
    __shared__ unsigned cur[128];
    const int tid = threadIdx.x;
    const int b = blockIdx.x;
    if (tid < 128) h[tid] = 0u;
    __syncthreads();
    const unsigned s = bucketBase[b];
    const unsigned e = bucketBase[b + 1];
    for (unsigned p = s + (unsigned)tid; p < e; p += 256u)
        atomicAdd(&h[sorted[p] >> 20], 1u);
    __syncthreads();
    if (tid < 128) sc[tid] = h[tid];
    __syncthreads();
    for (int off = 1; off < 128; off <<= 1) {
        unsigned t = 0;
        if (tid < 128 && tid >= off) t = sc[tid - off];
        __syncthreads();
        if (tid < 128) sc[tid] += t;
        __syncthreads();
    }
    if (tid < 128) {
        unsigned ex = sc[tid] - h[tid];
        cur[tid] = ex;
        int n = b * 128 + tid;
        if (n < N) {
            rsd[n] = h[tid] ? rsqrtf((float)h[tid]) : 0.f;
            rowptr[n] = s + ex;
        }
    }
    if (b == (int)gridDim.x - 1 && tid == 0) rowptr[N] = e;
    __syncthreads();
    for (unsigned p = s + (unsigned)tid; p < e; p += 256u) {
        unsigned m = sorted[p];
        unsigned pos = atomicAdd(&cur[m >> 20], 1u);
        sorted2[s + pos] = m & 0xFFFFFu;
    }
}

// ---------------------------------------------------------------------------
// K6: vbar2 via MFMA. Per wave-tile: 16 nodes x 32 d.
//   A: lane l -> xs[(n0+(l&15))*128 + kt*32 + (l>>4)*8 + j], j=0..7 (f32->bf16)
//   B: prepacked WTB with identical k-map
//   D: lane l, reg r -> node n0+(l>>4)*4+r, d = (l&15) + 16*dtile  [m89 layout]
// ---------------------------------------------------------------------------
__global__ __launch_bounds__(256) void vbar_kernel(
    const float* __restrict__ xs, const short* __restrict__ WTB,
    const float* __restrict__ bv, const float* __restrict__ rsd,
    float* __restrict__ vbar2, float* __restrict__ g_csum, int N)
{
    __shared__ float csum_lds[32];
    const int tid = threadIdx.x;
    if (tid < 32) csum_lds[tid] = 0.f;

    const int lane = tid & 63;
    const int col = lane & 15;
    const int grp = lane >> 4;

    // B fragments (2 d-tiles x 4 k-tiles), 16B coalesced per lane
    short8v bfr[2][4];
    const short8v* wtb = (const short8v*)WTB;
#pragma unroll
    for (int dt = 0; dt < 2; dt++)
#pragma unroll
        for (int kt = 0; kt < 4; kt++)
            bfr[dt][kt] = wtb[(dt * 4 + kt) * 64 + lane];

    const int d0 = col, d1 = col + 16;
    const float bb0 = 0.25f * (bv[d0] + bv[32 + d0] + bv[64 + d0] + bv[96 + d0]);
    const float bb1 = 0.25f * (bv[d1] + bv[32 + d1] + bv[64 + d1] + bv[96 + d1]);

    float cs0 = 0.f, cs1 = 0.f;
    const int ntiles = (N + 15) >> 4;
    const int wglob = blockIdx.x * 4 + (tid >> 6);
    const int nwaves = gridDim.x * 4;

    for (int t = wglob; t < ntiles; t += nwaves) {
        const int n0 = t * 16;
        const int rowg = min(n0 + col, N - 1);   // A-row for this lane (clamped tail)
        const float* xb = xs + (size_t)rowg * 128 + grp * 8;

        f32x4 alo[4], ahi[4];
#pragma unroll
        for (int kt = 0; kt < 4; kt++) {
            alo[kt] = *(const f32x4*)(xb + kt * 32);
            ahi[kt] = *(const f32x4*)(xb + kt * 32 + 4);
        }

        f32x4 acc0 = {0.f, 0.f, 0.f, 0.f};
        f32x4 acc1 = {0.f, 0.f, 0.f, 0.f};
#pragma unroll
        for (int kt = 0; kt < 4; kt++) {
            short8v af;
            af[0] = f2bf(alo[kt][0]); af[1] = f2bf(alo[kt][1]);
            af[2] = f2bf(alo[kt][2]); af[3] = f2bf(alo[kt][3]);
            af[4] = f2bf(ahi[kt][0]); af[5] = f2bf(ahi[kt][1]);
            af[6] = f2bf(ahi[kt][2]); af[7] = f2bf(ahi[kt][3]);
            bf16x8 a = __builtin_bit_cast(bf16x8, af);
            acc0 = __builtin_amdgcn_mfma_f32_16x16x32_bf16(
                a, __builtin_bit_cast(bf16x8, bfr[0][kt]), acc0, 0, 0, 0);
            acc1 = __builtin_amdgcn_mfma_f32_16x16x32_bf16(
                a, __builtin_bit_cast(bf16x8, bfr[1][kt]), acc1, 0, 0, 0);
        }

        const int rbase = n0 + grp * 4;
        const bool full = (n0 + 16 <= N);
        f32x4 rs4;
        if (full || rbase + 3 < N) rs4 = *(const f32x4*)(rsd + rbase);
        else { rs4[0] = rs4[1] = rs4[2] = rs4[3] = 0.f;
               for (int r = 0; r < 4; r++) if (rbase + r < N) rs4[r] = rsd[rbase + r]; }

#pragma unroll
        for (int r = 0; r < 4; r++) {
            int n = rbase + r;
            if (full || n < N) {
                float v0 = acc0[r] + bb0;
                float v1 = acc1[r] + bb1;
                float rv = rs4[r];
                vbar2[(size_t)n * 32 + d0] = v0 * rv;
                vbar2[(size_t)n * 32 + d1] = v1 * rv;
                cs0 += v0; cs1 += v1;
            }
        }
    }

    __syncthreads();
    atomicAdd(&csum_lds[d0], cs0);
    atomicAdd(&csum_lds[d1], cs1);
    __syncthreads();
    if (tid < 32) atomicAdd(&g_csum[tid], csum_lds[tid]);
}

// ---------------------------------------------------------------------------
// K7: per-node gather: out[n,d] = cst[d] + rsd[n] * sum_p vbar2[row_p, d]
// ---------------------------------------------------------------------------
__global__ __launch_bounds__(256) void gather_kernel(
    const unsigned* __restrict__ rowptr, const unsigned* __restrict__ sorted2,
    const float* __restrict__ vbar2, const float* __restrict__ g_csum,
    const float* __restrict__ rsd, float* __restrict__ out, int N, float invN)
{
    const int tid = threadIdx.x;
    const int n = blockIdx.x * 8 + (tid >> 5);
    const int d = tid & 31;
    if (n >= N) return;
    const unsigned s = rowptr[n];
    const unsigned e = rowptr[n + 1];
    float acc = 0.f;
    for (unsigned p0 = s; p0 < e; p0 += 32) {
        const int cnt = (int)min(32u, e - p0);
        unsigned pe = p0 + (unsigned)d;
        if (pe >= e) pe = e - 1;
        int m = (int)sorted2[pe];
        int j = 0;
        for (; j + 3 < cnt; j += 4) {
            int r0 = __shfl(m, j + 0, 32);
            int r1 = __shfl(m, j + 1, 32);
            int r2 = __shfl(m, j + 2, 32);
            int r3 = __shfl(m, j + 3, 32);
            float f0 = vbar2[(size_t)r0 * 32 + d];
            float f1 = vbar2[(size_t)r1 * 32 + d];
            float f2 = vbar2[(size_t)r2 * 32 + d];
            float f3 = vbar2[(size_t)r3 * 32 + d];
            acc += f0 + f1 + f2 + f3;
        }
        for (; j < cnt; j++) {
            int r0 = __shfl(m, j, 32);
            acc += vbar2[(size_t)r0 * 32 + d];
        }
    }
    out[(size_t)n * 32 + d] = g_csum[d] * invN + rsd[n] * acc;
}

// ---------------------------------------------------------------------------
extern "C" void kernel_launch(void* const* d_in, const int* in_sizes, int n_in,
                              void* d_out, int out_size, void* d_ws, size_t ws_size,
                              hipStream_t stream) {
    const float* xs = (const float*)d_in[1];
    const int*   ei = (const int*)d_in[2];
    const float* Wv = (const float*)d_in[7];
    const float* bv = (const float*)d_in[8];
    float* out = (float*)d_out;

    const int N = in_sizes[0] / 128;
    const int E = in_sizes[2] / 2;
    const int NBUK = (N + 127) >> 7;                 // 782
    const int chunk = (E + GRID_EDGE - 1) / GRID_EDGE;

    char* ws = (char*)d_ws;
    size_t o = 0;
    float*    vbar2      = (float*)(ws + o);    o += (size_t)N * 32 * 4;
    float*    rsd        = (float*)(ws + o);    o += (size_t)N * 4;
    float*    g_csum     = (float*)(ws + o);    o += 32 * 4;
    unsigned* rowptr     = (unsigned*)(ws + o); o += (size_t)(N + 1) * 4;
    unsigned* bcnt_pb    = (unsigned*)(ws + o); o += (size_t)GRID_EDGE * NBUK * 4;
    unsigned* partial_pb = (unsigned*)(ws + o); o += (size_t)NBUK * 1024 * 4;
    unsigned* colsum     = (unsigned*)(ws + o); o += (size_t)NBUK * 4;
    unsigned* bucketBase = (unsigned*)(ws + o); o += (size_t)(NBUK + 1) * 4;
    o = (o + 15) & ~(size_t)15;
    short*    WTB        = (short*)(ws + o);    o += 4096 * 2;
    unsigned* sorted     = (unsigned*)(ws + o); o += (size_t)E * 4;
    unsigned* sorted2    = (unsigned*)(ws + o); o += (size_t)E * 4;

    hipMemsetAsync(g_csum, 0, 32 * 4, stream);

    wt_kernel<<<2, 256, 0, stream>>>(Wv, WTB);
    hist_kernel<<<GRID_EDGE, 256, 0, stream>>>(ei, E, chunk, NBUK, bcnt_pb);
    scanPB_kernel<<<NBUK, 256, 0, stream>>>(bcnt_pb, NBUK, partial_pb, colsum);
    bucketScan_kernel<<<1, 256, 0, stream>>>(colsum, NBUK, E, bucketBase);
    fill_kernel<<<GRID_EDGE, 256, 0, stream>>>(ei, E, chunk, NBUK, partial_pb,
                                               bucketBase, sorted);
    sort_kernel<<<NBUK, 256, 0, stream>>>(bucketBase, sorted, rsd, rowptr, sorted2, N);
    vbar_kernel<<<1563, 256, 0, stream>>>(xs, WTB, bv, rsd, vbar2, g_csum, N);
    gather_kernel<<<(N + 7) / 8, 256, 0, stream>>>(rowptr, sorted2, vbar2, g_csum,
                                                   rsd, out, N, 1.0f / (float)N);
}

// Round 9
// 114.851 us; speedup vs baseline: 6.0465x; 1.0086x over previous
//
#include <hip/hip_runtime.h>
#include <hip/hip_bf16.h>

// N = 100000, E = 1600000, IN = 128, H = 4, D = 32
//
// Math (validated rounds 1-8, absmax 1.95e-3 vs threshold 8.2e-3):
//   vbar[n]  = xs[n] @ WT^T + bvbar          (WT[d][i] = 0.25*sum_h Wv[i][32h+d])
//   vbar2[n] = vbar[n] * (deg[n]? rsqrt(deg[n]) : 0)
//   cst[d]   = mean_n vbar[n,d]
//   out[n,d] = cst[d] + (deg[n]? rsqrt(deg[n]):0) * sum_{e:col=n} vbar2[row_e, d]
//
// Round-9: drop the hipMemsetAsync (its 128B fill cost ~39us of in-graph dead
// time per the round-8 trace); wt_kernel zeroes g_csum. Gather unrolled 8-wide
// for more outstanding random loads. Everything else unchanged from round 8.

#define GRID_EDGE 1024
#define MAXBUK 1024   // supports N <= 131072

typedef __attribute__((ext_vector_type(8))) short    short8v;
typedef __attribute__((ext_vector_type(8))) __bf16   bf16x8;
typedef __attribute__((ext_vector_type(4))) float    f32x4;

__device__ __forceinline__ short f2bf(float f) {
    unsigned u = __float_as_uint(f);
    unsigned r = (u + 0x7FFFu + ((u >> 16) & 1u)) >> 16;   // RNE
    return (short)r;
}

// ---------------------------------------------------------------------------
// K0: pack B fragments + zero g_csum. WTB[((dt*4+kt)*64+l)*8+j] = bf16(wt(k,d)),
//     k = kt*32 + (l>>4)*8 + j, d = dt*16 + (l&15),
//     wt(i,d) = 0.25*sum_h Wv[i*128+32h+d].
// ---------------------------------------------------------------------------
__global__ __launch_bounds__(256) void wt_kernel(const float* __restrict__ Wv,
                                                 short* __restrict__ WTB,
                                                 float* __restrict__ g_csum) {
    int idx = blockIdx.x * 256 + threadIdx.x;
    if (blockIdx.x == 0 && threadIdx.x < 32) g_csum[threadIdx.x] = 0.f;
    if (idx < 512) {
        int l = idx & 63;
        int kt = (idx >> 6) & 3;
        int dt = idx >> 8;
        int d = dt * 16 + (l & 15);
        int kbase = kt * 32 + (l >> 4) * 8;
#pragma unroll
        for (int j = 0; j < 8; j++) {
            int i = kbase + j;
            float w = 0.25f * (Wv[i * 128 + d] + Wv[i * 128 + 32 + d] +
                               Wv[i * 128 + 64 + d] + Wv[i * 128 + 96 + d]);
            WTB[idx * 8 + j] = f2bf(w);
        }
    }
}

// ---------------------------------------------------------------------------
// K1: per-block LDS bucket histogram -> bcnt_pb[block][NBUK] (coalesced store)
// ---------------------------------------------------------------------------
__global__ __launch_bounds__(256) void hist_kernel(const int* __restrict__ ei, int E,
                                                   int chunk, int NBUK,
                                                   unsigned* __restrict__ bcnt_pb) {
    __shared__ unsigned h[MAXBUK];
    const int tid = threadIdx.x;
    for (int k = tid; k < NBUK; k += 256) h[k] = 0u;
    __syncthreads();
    const int e0 = blockIdx.x * chunk;
    const int e1 = min(E, e0 + chunk);
    for (int e = e0 + tid; e < e1; e += 256)
        atomicAdd(&h[ei[E + e] >> 7], 1u);
    __syncthreads();
    unsigned* dst = bcnt_pb + (size_t)blockIdx.x * NBUK;
    for (int k = tid; k < NBUK; k += 256) dst[k] = h[k];
}

// ---------------------------------------------------------------------------
// K2: per-bucket exclusive scan over the 1024 blocks in XCD-major logical
// order i: physical block p(i) = (i&127)*8 + (i>>7).
// ---------------------------------------------------------------------------
__global__ __launch_bounds__(256) void scanPB_kernel(const unsigned* __restrict__ bcnt_pb,
                                                     int NBUK,
                                                     unsigned* __restrict__ partial_pb,
                                                     unsigned* __restrict__ colsum) {
    __shared__ unsigned s[256];
    const int b = blockIdx.x;
    const int tid = threadIdx.x;
    unsigned v[4], local = 0;
#pragma unroll
    for (int j = 0; j < 4; j++) {
        int i = tid * 4 + j;
        int p = (i & 127) * 8 + (i >> 7);
        v[j] = bcnt_pb[(size_t)p * NBUK + b];
        local += v[j];
    }
    s[tid] = local;
    __syncthreads();
    for (int off = 1; off < 256; off <<= 1) {
        unsigned t = (tid >= off) ? s[tid - off] : 0u;
        __syncthreads();
        s[tid] += t;
        __syncthreads();
    }
    unsigned run = s[tid] - local;
    unsigned* dst = partial_pb + (size_t)b * 1024;
#pragma unroll
    for (int j = 0; j < 4; j++) {
        dst[tid * 4 + j] = run;
        run += v[j];
    }
    if (tid == 255) colsum[b] = run;
}

// ---------------------------------------------------------------------------
// K3: exclusive scan of colsum -> bucketBase[NBUK+1]
// ---------------------------------------------------------------------------
__global__ __launch_bounds__(256) void bucketScan_kernel(const unsigned* __restrict__ colsum,
                                                         int NBUK, int E,
                                                         unsigned* __restrict__ bucketBase) {
    __shared__ unsigned s[256];
    const int tid = threadIdx.x;
    unsigned v[4], local = 0;
#pragma unroll
    for (int j = 0; j < 4; j++) {
        int i = tid * 4 + j;
        v[j] = (i < NBUK) ? colsum[i] : 0u;
        local += v[j];
    }
    s[tid] = local;
    __syncthreads();
    for (int off = 1; off < 256; off <<= 1) {
        unsigned t = (tid >= off) ? s[tid - off] : 0u;
        __syncthreads();
        s[tid] += t;
        __syncthreads();
    }
    unsigned run = s[tid] - local;
#pragma unroll
    for (int j = 0; j < 4; j++) {
        int i = tid * 4 + j;
        if (i < NBUK) bucketBase[i] = run;
        run += v[j];
    }
    if (tid == 0) bucketBase[NBUK] = (unsigned)E;
}

// ---------------------------------------------------------------------------
// K4: fill with per-block private LDS cursors (no global atomics).
// ---------------------------------------------------------------------------
__global__ __launch_bounds__(256) void fill_kernel(const int* __restrict__ ei, int E,
                                                   int chunk, int NBUK,
                                                   const unsigned* __restrict__ partial_pb,
                                                   const unsigned* __restrict__ bucketBase,
                                                   unsigned* __restrict__ sorted) {
    __shared__ unsigned cur[MAXBUK];
    const int tid = threadIdx.x;
    const int p = blockIdx.x;
    const int i = (p & 7) * 128 + (p >> 3);
    for (int k = tid; k < NBUK; k += 256)
        cur[k] = bucketBase[k] + partial_pb[(size_t)k * 1024 + i];
    __syncthreads();
    const int e0 = p * chunk;
    const int e1 = min(E, e0 + chunk);
    for (int e = e0 + tid; e < e1; e += 256) {
        int row = ei[e];
        int col = ei[E + e];
        unsigned pos = atomicAdd(&cur[col >> 7], 1u);
        sorted[pos] = (unsigned)row | ((unsigned)(col & 127) << 20);
    }
}

// ---------------------------------------------------------------------------
// K5: per-bucket counting sort + rsd + rowptr.
// ---------------------------------------------------------------------------
__global__ __launch_bounds__(256) void sort_kernel(
    const unsigned* __restrict__ bucketBase, const unsigned* __restrict__ sorted,
    float* __restrict__ rsd, unsigned* __restrict__ rowptr,
    unsigned* __restrict__ sorted2, int N)
{
    __shared__ unsigned h[128];
    __shared__ unsigned sc[128];
    __shared__ unsigned cur[128];
    const int tid = threadIdx.x;
    const int b = blockIdx.x;
    if (tid < 128) h[tid] = 0u;
    __syncthreads();
    const unsigned s = bucketBase[b];
    const unsigned e = bucketBase[b + 1];
    for (unsigned p = s + (unsigned)tid; p < e; p += 256u)
        atomicAdd(&h[sorted[p] >> 20], 1u);
    __syncthreads();
    if (tid < 128) sc[tid] = h[tid];
    __syncthreads();
    for (int off = 1; off < 128; off <<= 1) {
        unsigned t = 0;
        if (tid < 128 && tid >= off) t = sc[tid - off];
        __syncthreads();
        if (tid < 128) sc[tid] += t;
        __syncthreads();
    }
    if (tid < 128) {
        unsigned ex = sc[tid] - h[tid];
        cur[tid] = ex;
        int n = b * 128 + tid;
        if (n < N) {
            rsd[n] = h[tid] ? rsqrtf((float)h[tid]) : 0.f;
            rowptr[n] = s + ex;
        }
    }
    if (b == (int)gridDim.x - 1 && tid == 0) rowptr[N] = e;
    __syncthreads();
    for (unsigned p = s + (unsigned)tid; p < e; p += 256u) {
        unsigned m = sorted[p];
        unsigned pos = atomicAdd(&cur[m >> 20], 1u);
        sorted2[s + pos] = m & 0xFFFFFu;
    }
}

// ---------------------------------------------------------------------------
// K6: vbar2 via MFMA. Per wave-tile: 16 nodes x 32 d.
//   A: lane l -> xs[(n0+(l&15))*128 + kt*32 + (l>>4)*8 + j], j=0..7 (f32->bf16)
//   B: prepacked WTB with identical k-map
//   D: lane l, reg r -> node n0+(l>>4)*4+r, d = (l&15) + 16*dtile  [m89 layout]
// ---------------------------------------------------------------------------
__global__ __launch_bounds__(256) void vbar_kernel(
    const float* __restrict__ xs, const short* __restrict__ WTB,
    const float* __restrict__ bv, const float* __restrict__ rsd,
    float* __restrict__ vbar2, float* __restrict__ g_csum, int N)
{
    __shared__ float csum_lds[32];
    const int tid = threadIdx.x;
    if (tid < 32) csum_lds[tid] = 0.f;

    const int lane = tid & 63;
    const int col = lane & 15;
    const int grp = lane >> 4;

    short8v bfr[2][4];
    const short8v* wtb = (const short8v*)WTB;
#pragma unroll
    for (int dt = 0; dt < 2; dt++)
#pragma unroll
        for (int kt = 0; kt < 4; kt++)
            bfr[dt][kt] = wtb[(dt * 4 + kt) * 64 + lane];

    const int d0 = col, d1 = col + 16;
    const float bb0 = 0.25f * (bv[d0] + bv[32 + d0] + bv[64 + d0] + bv[96 + d0]);
    const float bb1 = 0.25f * (bv[d1] + bv[32 + d1] + bv[64 + d1] + bv[96 + d1]);

    float cs0 = 0.f, cs1 = 0.f;
    const int ntiles = (N + 15) >> 4;
    const int wglob = blockIdx.x * 4 + (tid >> 6);
    const int nwaves = gridDim.x * 4;

    for (int t = wglob; t < ntiles; t += nwaves) {
        const int n0 = t * 16;
        const int rowg = min(n0 + col, N - 1);
        const float* xb = xs + (size_t)rowg * 128 + grp * 8;

        f32x4 alo[4], ahi[4];
#pragma unroll
        for (int kt = 0; kt < 4; kt++) {
            alo[kt] = *(const f32x4*)(xb + kt * 32);
            ahi[kt] = *(const f32x4*)(xb + kt * 32 + 4);
        }

        f32x4 acc0 = {0.f, 0.f, 0.f, 0.f};
        f32x4 acc1 = {0.f, 0.f, 0.f, 0.f};
#pragma unroll
        for (int kt = 0; kt < 4; kt++) {
            short8v af;
            af[0] = f2bf(alo[kt][0]); af[1] = f2bf(alo[kt][1]);
            af[2] = f2bf(alo[kt][2]); af[3] = f2bf(alo[kt][3]);
            af[4] = f2bf(ahi[kt][0]); af[5] = f2bf(ahi[kt][1]);
            af[6] = f2bf(ahi[kt][2]); af[7] = f2bf(ahi[kt][3]);
            bf16x8 a = __builtin_bit_cast(bf16x8, af);
            acc0 = __builtin_amdgcn_mfma_f32_16x16x32_bf16(
                a, __builtin_bit_cast(bf16x8, bfr[0][kt]), acc0, 0, 0, 0);
            acc1 = __builtin_amdgcn_mfma_f32_16x16x32_bf16(
                a, __builtin_bit_cast(bf16x8, bfr[1][kt]), acc1, 0, 0, 0);
        }

        const int rbase = n0 + grp * 4;
        const bool full = (n0 + 16 <= N);
        f32x4 rs4;
        if (full || rbase + 3 < N) rs4 = *(const f32x4*)(rsd + rbase);
        else { rs4[0] = rs4[1] = rs4[2] = rs4[3] = 0.f;
               for (int r = 0; r < 4; r++) if (rbase + r < N) rs4[r] = rsd[rbase + r]; }

#pragma unroll
        for (int r = 0; r < 4; r++) {
            int n = rbase + r;
            if (full || n < N) {
                float v0 = acc0[r] + bb0;
                float v1 = acc1[r] + bb1;
                float rv = rs4[r];
                vbar2[(size_t)n * 32 + d0] = v0 * rv;
                vbar2[(size_t)n * 32 + d1] = v1 * rv;
                cs0 += v0; cs1 += v1;
            }
        }
    }

    __syncthreads();
    atomicAdd(&csum_lds[d0], cs0);
    atomicAdd(&csum_lds[d1], cs1);
    __syncthreads();
    if (tid < 32) atomicAdd(&g_csum[tid], csum_lds[tid]);
}

// ---------------------------------------------------------------------------
// K7: per-node gather: out[n,d] = cst[d] + rsd[n] * sum_p vbar2[row_p, d]
// 8-wide unroll: >=8 independent 128B vbar2 line loads in flight per group.
// ---------------------------------------------------------------------------
__global__ __launch_bounds__(256) void gather_kernel(
    const unsigned* __restrict__ rowptr, const unsigned* __restrict__ sorted2,
    const float* __restrict__ vbar2, const float* __restrict__ g_csum,
    const float* __restrict__ rsd, float* __restrict__ out, int N, float invN)
{
    const int tid = threadIdx.x;
    const int n = blockIdx.x * 8 + (tid >> 5);
    const int d = tid & 31;
    if (n >= N) return;
    const unsigned s = rowptr[n];
    const unsigned e = rowptr[n + 1];
    float acc = 0.f;
    for (unsigned p0 = s; p0 < e; p0 += 32) {
        const int cnt = (int)min(32u, e - p0);
        unsigned pe = p0 + (unsigned)d;
        if (pe >= e) pe = e - 1;
        int m = (int)sorted2[pe];
        int j = 0;
        for (; j + 7 < cnt; j += 8) {
            int r0 = __shfl(m, j + 0, 32);
            int r1 = __shfl(m, j + 1, 32);
            int r2 = __shfl(m, j + 2, 32);
            int r3 = __shfl(m, j + 3, 32);
            int r4 = __shfl(m, j + 4, 32);
            int r5 = __shfl(m, j + 5, 32);
            int r6 = __shfl(m, j + 6, 32);
            int r7 = __shfl(m, j + 7, 32);
            float f0 = vbar2[(size_t)r0 * 32 + d];
            float f1 = vbar2[(size_t)r1 * 32 + d];
            float f2 = vbar2[(size_t)r2 * 32 + d];
            float f3 = vbar2[(size_t)r3 * 32 + d];
            float f4 = vbar2[(size_t)r4 * 32 + d];
            float f5 = vbar2[(size_t)r5 * 32 + d];
            float f6 = vbar2[(size_t)r6 * 32 + d];
            float f7 = vbar2[(size_t)r7 * 32 + d];
            acc += ((f0 + f1) + (f2 + f3)) + ((f4 + f5) + (f6 + f7));
        }
        for (; j < cnt; j++) {
            int r0 = __shfl(m, j, 32);
            acc += vbar2[(size_t)r0 * 32 + d];
        }
    }
    out[(size_t)n * 32 + d] = g_csum[d] * invN + rsd[n] * acc;
}

// ---------------------------------------------------------------------------
extern "C" void kernel_launch(void* const* d_in, const int* in_sizes, int n_in,
                              void* d_out, int out_size, void* d_ws, size_t ws_size,
                              hipStream_t stream) {
    const float* xs = (const float*)d_in[1];
    const int*   ei = (const int*)d_in[2];
    const float* Wv = (const float*)d_in[7];
    const float* bv = (const float*)d_in[8];
    float* out = (float*)d_out;

    const int N = in_sizes[0] / 128;
    const int E = in_sizes[2] / 2;
    const int NBUK = (N + 127) >> 7;                 // 782
    const int chunk = (E + GRID_EDGE - 1) / GRID_EDGE;

    char* ws = (char*)d_ws;
    size_t o = 0;
    float*    vbar2      = (float*)(ws + o);    o += (size_t)N * 32 * 4;
    float*    rsd        = (float*)(ws + o);    o += (size_t)N * 4;
    float*    g_csum     = (float*)(ws + o);    o += 32 * 4;
    unsigned* rowptr     = (unsigned*)(ws + o); o += (size_t)(N + 1) * 4;
    unsigned* bcnt_pb    = (unsigned*)(ws + o); o += (size_t)GRID_EDGE * NBUK * 4;
    unsigned* partial_pb = (unsigned*)(ws + o); o += (size_t)NBUK * 1024 * 4;
    unsigned* colsum     = (unsigned*)(ws + o); o += (size_t)NBUK * 4;
    unsigned* bucketBase = (unsigned*)(ws + o); o += (size_t)(NBUK + 1) * 4;
    o = (o + 15) & ~(size_t)15;
    short*    WTB        = (short*)(ws + o);    o += 4096 * 2;
    unsigned* sorted     = (unsigned*)(ws + o); o += (size_t)E * 4;
    unsigned* sorted2    = (unsigned*)(ws + o); o += (size_t)E * 4;

    wt_kernel<<<2, 256, 0, stream>>>(Wv, WTB, g_csum);
    hist_kernel<<<GRID_EDGE, 256, 0, stream>>>(ei, E, chunk, NBUK, bcnt_pb);
    scanPB_kernel<<<NBUK, 256, 0, stream>>>(bcnt_pb, NBUK, partial_pb, colsum);
    bucketScan_kernel<<<1, 256, 0, stream>>>(colsum, NBUK, E, bucketBase);
    fill_kernel<<<GRID_EDGE, 256, 0, stream>>>(ei, E, chunk, NBUK, partial_pb,
                                               bucketBase, sorted);
    sort_kernel<<<NBUK, 256, 0, stream>>>(bucketBase, sorted, rsd, rowptr, sorted2, N);
    vbar_kernel<<<1563, 256, 0, stream>>>(xs, WTB, bv, rsd, vbar2, g_csum, N);
    gather_kernel<<<(N + 7) / 8, 256, 0, stream>>>(rowptr, sorted2, vbar2, g_csum,
                                                   rsd, out, N, 1.0f / (float)N);
}

// Round 10
// 112.549 us; speedup vs baseline: 6.1702x; 1.0205x over previous
//
#include <hip/hip_runtime.h>
#include <hip/hip_bf16.h>

// N = 100000, E = 1600000, IN = 128, H = 4, D = 32
//
// Math (validated rounds 1-9, absmax 1.95e-3 vs threshold 8.2e-3):
//   vbar[n]  = xs[n] @ WT^T + bvbar          (WT[d][i] = 0.25*sum_h Wv[i][32h+d])
//   vbar2[n] = vbar[n] * (deg[n]? rsqrt(deg[n]) : 0)       [stored bf16 now]
//   cst[d]   = mean_n vbar[n,d]   (accumulated in f32 pre-rounding)
//   out[n,d] = cst[d] + (deg[n]? rsqrt(deg[n]):0) * sum_{e:col=n} vbar2[row_e, d]
//
// Round-10: (a) GRID_EDGE 1024->256 — kills the 16x fetch amplification in
// scanPB/fill transposed reads (4B touches at 3KB stride); (b) vbar2 stored
// as bf16 — halves gather's random line fetch and the vbar2 write traffic.
// Edge path structure (zero global atomics) and MFMA vbar otherwise unchanged.

#define GRID_EDGE 256
#define MAXBUK 1024   // supports N <= 131072

typedef __attribute__((ext_vector_type(8))) short    short8v;
typedef __attribute__((ext_vector_type(8))) __bf16   bf16x8;
typedef __attribute__((ext_vector_type(4))) float    f32x4;

__device__ __forceinline__ short f2bf(float f) {
    unsigned u = __float_as_uint(f);
    unsigned r = (u + 0x7FFFu + ((u >> 16) & 1u)) >> 16;   // RNE
    return (short)r;
}
__device__ __forceinline__ float bf2f(unsigned short v) {
    return __uint_as_float((unsigned)v << 16);
}

// ---------------------------------------------------------------------------
// K0: pack B fragments + zero g_csum. WTB[((dt*4+kt)*64+l)*8+j] = bf16(wt(k,d)),
//     k = kt*32 + (l>>4)*8 + j, d = dt*16 + (l&15),
//     wt(i,d) = 0.25*sum_h Wv[i*128+32h+d].
// ---------------------------------------------------------------------------
__global__ __launch_bounds__(256) void wt_kernel(const float* __restrict__ Wv,
                                                 short* __restrict__ WTB,
                                                 float* __restrict__ g_csum) {
    int idx = blockIdx.x * 256 + threadIdx.x;
    if (blockIdx.x == 0 && threadIdx.x < 32) g_csum[threadIdx.x] = 0.f;
    if (idx < 512) {
        int l = idx & 63;
        int kt = (idx >> 6) & 3;
        int dt = idx >> 8;
        int d = dt * 16 + (l & 15);
        int kbase = kt * 32 + (l >> 4) * 8;
#pragma unroll
        for (int j = 0; j < 8; j++) {
            int i = kbase + j;
            float w = 0.25f * (Wv[i * 128 + d] + Wv[i * 128 + 32 + d] +
                               Wv[i * 128 + 64 + d] + Wv[i * 128 + 96 + d]);
            WTB[idx * 8 + j] = f2bf(w);
        }
    }
}

// ---------------------------------------------------------------------------
// K1: per-block LDS bucket histogram -> bcnt_pb[block][NBUK] (coalesced store)
// ---------------------------------------------------------------------------
__global__ __launch_bounds__(256) void hist_kernel(const int* __restrict__ ei, int E,
                                                   int chunk, int NBUK,
                                                   unsigned* __restrict__ bcnt_pb) {
    __shared__ unsigned h[MAXBUK];
    const int tid = threadIdx.x;
    for (int k = tid; k < NBUK; k += 256) h[k] = 0u;
    __syncthreads();
    const int e0 = blockIdx.x * chunk;
    const int e1 = min(E, e0 + chunk);
    for (int e = e0 + tid; e < e1; e += 256)
        atomicAdd(&h[ei[E + e] >> 7], 1u);
    __syncthreads();
    unsigned* dst = bcnt_pb + (size_t)blockIdx.x * NBUK;
    for (int k = tid; k < NBUK; k += 256) dst[k] = h[k];
}

// ---------------------------------------------------------------------------
// K2: per-bucket exclusive scan over the 256 blocks in XCD-major logical
// order i: physical block p(i) = (i>>5) | ((i&31)<<3)  (p&7 = i>>5).
// ---------------------------------------------------------------------------
__global__ __launch_bounds__(256) void scanPB_kernel(const unsigned* __restrict__ bcnt_pb,
                                                     int NBUK,
                                                     unsigned* __restrict__ partial_pb,
                                                     unsigned* __restrict__ colsum) {
    __shared__ unsigned s[256];
    const int b = blockIdx.x;
    const int tid = threadIdx.x;
    const int p = ((tid >> 5) & 7) | ((tid & 31) << 3);
    unsigned v = bcnt_pb[(size_t)p * NBUK + b];
    s[tid] = v;
    __syncthreads();
    for (int off = 1; off < 256; off <<= 1) {
        unsigned t = (tid >= off) ? s[tid - off] : 0u;
        __syncthreads();
        s[tid] += t;
        __syncthreads();
    }
    partial_pb[(size_t)b * 256 + tid] = s[tid] - v;
    if (tid == 255) colsum[b] = s[255];
}

// ---------------------------------------------------------------------------
// K3: exclusive scan of colsum -> bucketBase[NBUK+1]
// ---------------------------------------------------------------------------
__global__ __launch_bounds__(256) void bucketScan_kernel(const unsigned* __restrict__ colsum,
                                                         int NBUK, int E,
                                                         unsigned* __restrict__ bucketBase) {
    __shared__ unsigned s[256];
    const int tid = threadIdx.x;
    unsigned v[4], local = 0;
#pragma unroll
    for (int j = 0; j < 4; j++) {
        int i = tid * 4 + j;
        v[j] = (i < NBUK) ? colsum[i] : 0u;
        local += v[j];
    }
    s[tid] = local;
    __syncthreads();
    for (int off = 1; off < 256; off <<= 1) {
        unsigned t = (tid >= off) ? s[tid - off] : 0u;
        __syncthreads();
        s[tid] += t;
        __syncthreads();
    }
    unsigned run = s[tid] - local;
#pragma unroll
    for (int j = 0; j < 4; j++) {
        int i = tid * 4 + j;
        if (i < NBUK) bucketBase[i] = run;
        run += v[j];
    }
    if (tid == 0) bucketBase[NBUK] = (unsigned)E;
}

// ---------------------------------------------------------------------------
// K4: fill with per-block private LDS cursors (no global atomics).
// i(p) = (p&7)*32 + (p>>3).
// ---------------------------------------------------------------------------
__global__ __launch_bounds__(256) void fill_kernel(const int* __restrict__ ei, int E,
                                                   int chunk, int NBUK,
                                                   const unsigned* __restrict__ partial_pb,
                                                   const unsigned* __restrict__ bucketBase,
                                                   unsigned* __restrict__ sorted) {
    __shared__ unsigned cur[MAXBUK];
    const int tid = threadIdx.x;
    const int p = blockIdx.x;
    const int i = (p & 7) * 32 + (p >> 3);
    for (int k = tid; k < NBUK; k += 256)
        cur[k] = bucketBase[k] + partial_pb[(size_t)k * 256 + i];
    __syncthreads();
    const int e0 = p * chunk;
    const int e1 = min(E, e0 + chunk);
    for (int e = e0 + tid; e < e1; e += 256) {
        int row = ei[e];
        int col = ei[E + e];
        unsigned pos = atomicAdd(&cur[col >> 7], 1u);
        sorted[pos] = (unsigned)row | ((unsigned)(col & 127) << 20);
    }
}

// ---------------------------------------------------------------------------
// K5: per-bucket counting sort + rsd + rowptr.
// ---------------------------------------------------------------------------
__global__ __launch_bounds__(256) void sort_kernel(
    const unsigned* __restrict__ bucketBase, const unsigned* __restrict__ sorted,
    float* __restrict__ rsd, unsigned* __restrict__ rowptr,
    unsigned* __restrict__ sorted2, int N)
{
    __shared__ unsigned h[128];
    __shared__ unsigned sc[128];
    __shared__ unsigned cur[128];
    const int tid = threadIdx.x;
    const int b = blockIdx.x;
    if (tid < 128) h[tid] = 0u;
    __syncthreads();
    const unsigned s = bucketBase[b];
    const unsigned e = bucketBase[b + 1];
    for (unsigned p = s + (unsigned)tid; p < e; p += 256u)
        atomicAdd(&h[sorted[p] >> 20], 1u);
    __syncthreads();
    if (tid < 128) sc[tid] = h[tid];
    __syncthreads();
    for (int off = 1; off < 128; off <<= 1) {
        unsigned t = 0;
        if (tid < 128 && tid >= off) t = sc[tid - off];
        __syncthreads();
        if (tid < 128) sc[tid] += t;
        __syncthreads();
    }
    if (tid < 128) {
        unsigned ex = sc[tid] - h[tid];
        cur[tid] = ex;
        int n = b * 128 + tid;
        if (n < N) {
            rsd[n] = h[tid] ? rsqrtf((float)h[tid]) : 0.f;
            rowptr[n] = s + ex;
        }
    }
    if (b == (int)gridDim.x - 1 && tid == 0) rowptr[N] = e;
    __syncthreads();
    for (unsigned p = s + (unsigned)tid; p < e; p += 256u) {
        unsigned m = sorted[p];
        unsigned pos = atomicAdd(&cur[m >> 20], 1u);
        sorted2[s + pos] = m & 0xFFFFFu;
    }
}

// ---------------------------------------------------------------------------
// K6: vbar2 (bf16) via MFMA. Per wave-tile: 16 nodes x 32 d.
//   A: lane l -> xs[(n0+(l&15))*128 + kt*32 + (l>>4)*8 + j], j=0..7 (f32->bf16)
//   B: prepacked WTB with identical k-map
//   D: lane l, reg r -> node n0+(l>>4)*4+r, d = (l&15) + 16*dtile  [m89 layout]
// ---------------------------------------------------------------------------
__global__ __launch_bounds__(256) void vbar_kernel(
    const float* __restrict__ xs, const short* __restrict__ WTB,
    const float* __restrict__ bv, const float* __restrict__ rsd,
    unsigned short* __restrict__ vbar2b, float* __restrict__ g_csum, int N)
{
    __shared__ float csum_lds[32];
    const int tid = threadIdx.x;
    if (tid < 32) csum_lds[tid] = 0.f;

    const int lane = tid & 63;
    const int col = lane & 15;
    const int grp = lane >> 4;

    short8v bfr[2][4];
    const short8v* wtb = (const short8v*)WTB;
#pragma unroll
    for (int dt = 0; dt < 2; dt++)
#pragma unroll
        for (int kt = 0; kt < 4; kt++)
            bfr[dt][kt] = wtb[(dt * 4 + kt) * 64 + lane];

    const int d0 = col, d1 = col + 16;
    const float bb0 = 0.25f * (bv[d0] + bv[32 + d0] + bv[64 + d0] + bv[96 + d0]);
    const float bb1 = 0.25f * (bv[d1] + bv[32 + d1] + bv[64 + d1] + bv[96 + d1]);

    float cs0 = 0.f, cs1 = 0.f;
    const int ntiles = (N + 15) >> 4;
    const int wglob = blockIdx.x * 4 + (tid >> 6);
    const int nwaves = gridDim.x * 4;

    for (int t = wglob; t < ntiles; t += nwaves) {
        const int n0 = t * 16;
        const int rowg = min(n0 + col, N - 1);
        const float* xb = xs + (size_t)rowg * 128 + grp * 8;

        f32x4 alo[4], ahi[4];
#pragma unroll
        for (int kt = 0; kt < 4; kt++) {
            alo[kt] = *(const f32x4*)(xb + kt * 32);
            ahi[kt] = *(const f32x4*)(xb + kt * 32 + 4);
        }

        f32x4 acc0 = {0.f, 0.f, 0.f, 0.f};
        f32x4 acc1 = {0.f, 0.f, 0.f, 0.f};
#pragma unroll
        for (int kt = 0; kt < 4; kt++) {
            short8v af;
            af[0] = f2bf(alo[kt][0]); af[1] = f2bf(alo[kt][1]);
            af[2] = f2bf(alo[kt][2]); af[3] = f2bf(alo[kt][3]);
            af[4] = f2bf(ahi[kt][0]); af[5] = f2bf(ahi[kt][1]);
            af[6] = f2bf(ahi[kt][2]); af[7] = f2bf(ahi[kt][3]);
            bf16x8 a = __builtin_bit_cast(bf16x8, af);
            acc0 = __builtin_amdgcn_mfma_f32_16x16x32_bf16(
                a, __builtin_bit_cast(bf16x8, bfr[0][kt]), acc0, 0, 0, 0);
            acc1 = __builtin_amdgcn_mfma_f32_16x16x32_bf16(
                a, __builtin_bit_cast(bf16x8, bfr[1][kt]), acc1, 0, 0, 0);
        }

        const int rbase = n0 + grp * 4;
        const bool full = (n0 + 16 <= N);
        f32x4 rs4;
        if (full || rbase + 3 < N) rs4 = *(const f32x4*)(rsd + rbase);
        else { rs4[0] = rs4[1] = rs4[2] = rs4[3] = 0.f;
               for (int r = 0; r < 4; r++) if (rbase + r < N) rs4[r] = rsd[rbase + r]; }

#pragma unroll
        for (int r = 0; r < 4; r++) {
            int n = rbase + r;
            if (full || n < N) {
                float v0 = acc0[r] + bb0;
                float v1 = acc1[r] + bb1;
                float rv = rs4[r];
                vbar2b[(size_t)n * 32 + d0] = (unsigned short)f2bf(v0 * rv);
                vbar2b[(size_t)n * 32 + d1] = (unsigned short)f2bf(v1 * rv);
                cs0 += v0; cs1 += v1;
            }
        }
    }

    __syncthreads();
    atomicAdd(&csum_lds[d0], cs0);
    atomicAdd(&csum_lds[d1], cs1);
    __syncthreads();
    if (tid < 32) atomicAdd(&g_csum[tid], csum_lds[tid]);
}

// ---------------------------------------------------------------------------
// K7: per-node gather: out[n,d] = cst[d] + rsd[n] * sum_p bf2f(vbar2b[row_p, d])
// 8-wide unroll: >=8 independent 64B vbar2b line loads in flight per group.
// ---------------------------------------------------------------------------
__global__ __launch_bounds__(256) void gather_kernel(
    const unsigned* __restrict__ rowptr, const unsigned* __restrict__ sorted2,
    const unsigned short* __restrict__ vbar2b, const float* __restrict__ g_csum,
    const float* __restrict__ rsd, float* __restrict__ out, int N, float invN)
{
    const int tid = threadIdx.x;
    const int n = blockIdx.x * 8 + (tid >> 5);
    const int d = tid & 31;
    if (n >= N) return;
    const unsigned s = rowptr[n];
    const unsigned e = rowptr[n + 1];
    float acc = 0.f;
    for (unsigned p0 = s; p0 < e; p0 += 32) {
        const int cnt = (int)min(32u, e - p0);
        unsigned pe = p0 + (unsigned)d;
        if (pe >= e) pe = e - 1;
        int m = (int)sorted2[pe];
        int j = 0;
        for (; j + 7 < cnt; j += 8) {
            int r0 = __shfl(m, j + 0, 32);
            int r1 = __shfl(m, j + 1, 32);
            int r2 = __shfl(m, j + 2, 32);
            int r3 = __shfl(m, j + 3, 32);
            int r4 = __shfl(m, j + 4, 32);
            int r5 = __shfl(m, j + 5, 32);
            int r6 = __shfl(m, j + 6, 32);
            int r7 = __shfl(m, j + 7, 32);
            float f0 = bf2f(vbar2b[(size_t)r0 * 32 + d]);
            float f1 = bf2f(vbar2b[(size_t)r1 * 32 + d]);
            float f2 = bf2f(vbar2b[(size_t)r2 * 32 + d]);
            float f3 = bf2f(vbar2b[(size_t)r3 * 32 + d]);
            float f4 = bf2f(vbar2b[(size_t)r4 * 32 + d]);
            float f5 = bf2f(vbar2b[(size_t)r5 * 32 + d]);
            float f6 = bf2f(vbar2b[(size_t)r6 * 32 + d]);
            float f7 = bf2f(vbar2b[(size_t)r7 * 32 + d]);
            acc += ((f0 + f1) + (f2 + f3)) + ((f4 + f5) + (f6 + f7));
        }
        for (; j < cnt; j++) {
            int r0 = __shfl(m, j, 32);
            acc += bf2f(vbar2b[(size_t)r0 * 32 + d]);
        }
    }
    out[(size_t)n * 32 + d] = g_csum[d] * invN + rsd[n] * acc;
}

// ---------------------------------------------------------------------------
extern "C" void kernel_launch(void* const* d_in, const int* in_sizes, int n_in,
                              void* d_out, int out_size, void* d_ws, size_t ws_size,
                              hipStream_t stream) {
    const float* xs = (const float*)d_in[1];
    const int*   ei = (const int*)d_in[2];
    const float* Wv = (const float*)d_in[7];
    const float* bv = (const float*)d_in[8];
    float* out = (float*)d_out;

    const int N = in_sizes[0] / 128;
    const int E = in_sizes[2] / 2;
    const int NBUK = (N + 127) >> 7;                 // 782
    const int chunk = (E + GRID_EDGE - 1) / GRID_EDGE;

    char* ws = (char*)d_ws;
    size_t o = 0;
    unsigned short* vbar2b = (unsigned short*)(ws + o); o += (size_t)N * 32 * 2;
    o = (o + 15) & ~(size_t)15;
    float*    rsd        = (float*)(ws + o);    o += (size_t)N * 4;
    float*    g_csum     = (float*)(ws + o);    o += 32 * 4;
    unsigned* rowptr     = (unsigned*)(ws + o); o += (size_t)(N + 1) * 4;
    unsigned* bcnt_pb    = (unsigned*)(ws + o); o += (size_t)GRID_EDGE * NBUK * 4;
    unsigned* partial_pb = (unsigned*)(ws + o); o += (size_t)NBUK * 256 * 4;
    unsigned* colsum     = (unsigned*)(ws + o); o += (size_t)NBUK * 4;
    unsigned* bucketBase = (unsigned*)(ws + o); o += (size_t)(NBUK + 1) * 4;
    o = (o + 15) & ~(size_t)15;
    short*    WTB        = (short*)(ws + o);    o += 4096 * 2;
    unsigned* sorted     = (unsigned*)(ws + o); o += (size_t)E * 4;
    unsigned* sorted2    = (unsigned*)(ws + o); o += (size_t)E * 4;

    wt_kernel<<<2, 256, 0, stream>>>(Wv, WTB, g_csum);
    hist_kernel<<<GRID_EDGE, 256, 0, stream>>>(ei, E, chunk, NBUK, bcnt_pb);
    scanPB_kernel<<<NBUK, 256, 0, stream>>>(bcnt_pb, NBUK, partial_pb, colsum);
    bucketScan_kernel<<<1, 256, 0, stream>>>(colsum, NBUK, E, bucketBase);
    fill_kernel<<<GRID_EDGE, 256, 0, stream>>>(ei, E, chunk, NBUK, partial_pb,
                                               bucketBase, sorted);
    sort_kernel<<<NBUK, 256, 0, stream>>>(bucketBase, sorted, rsd, rowptr, sorted2, N);
    vbar_kernel<<<1563, 256, 0, stream>>>(xs, WTB, bv, rsd, vbar2b, g_csum, N);
    gather_kernel<<<(N + 7) / 8, 256, 0, stream>>>(rowptr, sorted2, vbar2b, g_csum,
                                                   rsd, out, N, 1.0f / (float)N);
}

// Round 11
// 109.255 us; speedup vs baseline: 6.3562x; 1.0301x over previous
//
#include <hip/hip_runtime.h>
#include <hip/hip_bf16.h>

// N = 100000, E = 1600000, IN = 128, H = 4, D = 32
//
// Math (validated rounds 1-10, absmax 1.95e-3 vs threshold 8.2e-3):
//   vbar[n]  = xs[n] @ WT^T + bvbar          (WT[d][i] = 0.25*sum_h Wv[i][32h+d])
//   vbar2[n] = vbar[n] * (deg[n]? rsqrt(deg[n]) : 0)       [bf16]
//   cst[d]   = mean_n vbar[n,d]   (f32 accumulation pre-rounding)
//   out[n,d] = cst[d] + (deg[n]? rsqrt(deg[n]):0) * sum_{e:col=n} vbar2[row_e, d]
//
// Round-11: (a) vbar stores UNSCALED bf16 (no rsd dependency) and the
// rsqrt(deg) fold moves into sort's epilogue (deg already in its LDS);
// (b) vbar + hist fused into one kernel via blockIdx split — the MFMA
// blocks and latency-bound histogram blocks co-schedule, time ~= max not sum;
// (c) GRID_EDGE back to 512 for fill occupancy (2 blocks/CU).

#define GRID_EDGE 512
#define MAXBUK 1024   // supports N <= 131072

typedef __attribute__((ext_vector_type(8))) short    short8v;
typedef __attribute__((ext_vector_type(8))) __bf16   bf16x8;
typedef __attribute__((ext_vector_type(4))) float    f32x4;

__device__ __forceinline__ short f2bf(float f) {
    unsigned u = __float_as_uint(f);
    unsigned r = (u + 0x7FFFu + ((u >> 16) & 1u)) >> 16;   // RNE
    return (short)r;
}
__device__ __forceinline__ float bf2f(unsigned short v) {
    return __uint_as_float((unsigned)v << 16);
}

// ---------------------------------------------------------------------------
// K0: pack B fragments + zero g_csum. WTB[((dt*4+kt)*64+l)*8+j] = bf16(wt(k,d)),
//     k = kt*32 + (l>>4)*8 + j, d = dt*16 + (l&15),
//     wt(i,d) = 0.25*sum_h Wv[i*128+32h+d].
// ---------------------------------------------------------------------------
__global__ __launch_bounds__(256) void wt_kernel(const float* __restrict__ Wv,
                                                 short* __restrict__ WTB,
                                                 float* __restrict__ g_csum) {
    int idx = blockIdx.x * 256 + threadIdx.x;
    if (blockIdx.x == 0 && threadIdx.x < 32) g_csum[threadIdx.x] = 0.f;
    if (idx < 512) {
        int l = idx & 63;
        int kt = (idx >> 6) & 3;
        int dt = idx >> 8;
        int d = dt * 16 + (l & 15);
        int kbase = kt * 32 + (l >> 4) * 8;
#pragma unroll
        for (int j = 0; j < 8; j++) {
            int i = kbase + j;
            float w = 0.25f * (Wv[i * 128 + d] + Wv[i * 128 + 32 + d] +
                               Wv[i * 128 + 64 + d] + Wv[i * 128 + 96 + d]);
            WTB[idx * 8 + j] = f2bf(w);
        }
    }
}

// ---------------------------------------------------------------------------
// K1 (fused): blocks [0, VB): vbar (MFMA, unscaled bf16 + csum)
//             blocks [VB, VB+GRID_EDGE): per-block LDS bucket histogram
// vbar A: lane l -> xs[(n0+(l&15))*128 + kt*32 + (l>>4)*8 + j]  (f32->bf16)
//      D: lane l, reg r -> node n0+(l>>4)*4+r, d = (l&15)+16*dt  [m89 layout]
// ---------------------------------------------------------------------------
__global__ __launch_bounds__(256) void fused_kernel(
    const float* __restrict__ xs, const short* __restrict__ WTB,
    const float* __restrict__ bv, unsigned short* __restrict__ vbarb,
    float* __restrict__ g_csum, int N, int VB,
    const int* __restrict__ ei, int E, int chunk, int NBUK,
    unsigned* __restrict__ bcnt_pb)
{
    __shared__ float csum_lds[32];
    __shared__ unsigned h[MAXBUK];
    const int tid = threadIdx.x;

    if ((int)blockIdx.x >= VB) {
        // ---------------- histogram part ----------------
        const int p = blockIdx.x - VB;
        for (int k = tid; k < NBUK; k += 256) h[k] = 0u;
        __syncthreads();
        const int e0 = p * chunk;
        const int e1 = min(E, e0 + chunk);
        for (int e = e0 + tid; e < e1; e += 256)
            atomicAdd(&h[ei[E + e] >> 7], 1u);
        __syncthreads();
        unsigned* dst = bcnt_pb + (size_t)p * NBUK;
        for (int k = tid; k < NBUK; k += 256) dst[k] = h[k];
        return;
    }

    // ---------------- vbar part ----------------
    if (tid < 32) csum_lds[tid] = 0.f;

    const int lane = tid & 63;
    const int col = lane & 15;
    const int grp = lane >> 4;

    short8v bfr[2][4];
    const short8v* wtb = (const short8v*)WTB;
#pragma unroll
    for (int dt = 0; dt < 2; dt++)
#pragma unroll
        for (int kt = 0; kt < 4; kt++)
            bfr[dt][kt] = wtb[(dt * 4 + kt) * 64 + lane];

    const int d0 = col, d1 = col + 16;
    const float bb0 = 0.25f * (bv[d0] + bv[32 + d0] + bv[64 + d0] + bv[96 + d0]);
    const float bb1 = 0.25f * (bv[d1] + bv[32 + d1] + bv[64 + d1] + bv[96 + d1]);

    float cs0 = 0.f, cs1 = 0.f;
    const int ntiles = (N + 15) >> 4;
    const int wglob = blockIdx.x * 4 + (tid >> 6);
    const int nwaves = VB * 4;

    for (int t = wglob; t < ntiles; t += nwaves) {
        const int n0 = t * 16;
        const int rowg = min(n0 + col, N - 1);
        const float* xb = xs + (size_t)rowg * 128 + grp * 8;

        f32x4 alo[4], ahi[4];
#pragma unroll
        for (int kt = 0; kt < 4; kt++) {
            alo[kt] = *(const f32x4*)(xb + kt * 32);
            ahi[kt] = *(const f32x4*)(xb + kt * 32 + 4);
        }

        f32x4 acc0 = {0.f, 0.f, 0.f, 0.f};
        f32x4 acc1 = {0.f, 0.f, 0.f, 0.f};
#pragma unroll
        for (int kt = 0; kt < 4; kt++) {
            short8v af;
            af[0] = f2bf(alo[kt][0]); af[1] = f2bf(alo[kt][1]);
            af[2] = f2bf(alo[kt][2]); af[3] = f2bf(alo[kt][3]);
            af[4] = f2bf(ahi[kt][0]); af[5] = f2bf(ahi[kt][1]);
            af[6] = f2bf(ahi[kt][2]); af[7] = f2bf(ahi[kt][3]);
            bf16x8 a = __builtin_bit_cast(bf16x8, af);
            acc0 = __builtin_amdgcn_mfma_f32_16x16x32_bf16(
                a, __builtin_bit_cast(bf16x8, bfr[0][kt]), acc0, 0, 0, 0);
            acc1 = __builtin_amdgcn_mfma_f32_16x16x32_bf16(
                a, __builtin_bit_cast(bf16x8, bfr[1][kt]), acc1, 0, 0, 0);
        }

        const int rbase = n0 + grp * 4;
        const bool full = (n0 + 16 <= N);
#pragma unroll
        for (int r = 0; r < 4; r++) {
            int n = rbase + r;
            if (full || n < N) {
                float v0 = acc0[r] + bb0;
                float v1 = acc1[r] + bb1;
                vbarb[(size_t)n * 32 + d0] = (unsigned short)f2bf(v0);
                vbarb[(size_t)n * 32 + d1] = (unsigned short)f2bf(v1);
                cs0 += v0; cs1 += v1;
            }
        }
    }

    __syncthreads();
    atomicAdd(&csum_lds[d0], cs0);
    atomicAdd(&csum_lds[d1], cs1);
    __syncthreads();
    if (tid < 32) atomicAdd(&g_csum[tid], csum_lds[tid]);
}

// ---------------------------------------------------------------------------
// K2: per-bucket exclusive scan over the 512 blocks in XCD-major logical
// order i (p(i) = (i>>6) + ((i&63)<<3), so p%8 = i>>6).
// ---------------------------------------------------------------------------
__global__ __launch_bounds__(256) void scanPB_kernel(const unsigned* __restrict__ bcnt_pb,
                                                     int NBUK,
                                                     unsigned* __restrict__ partial_pb,
                                                     unsigned* __restrict__ colsum) {
    __shared__ unsigned s[256];
    const int b = blockIdx.x;
    const int tid = threadIdx.x;
    const int i0 = tid * 2, i1 = tid * 2 + 1;
    const int p0 = (i0 >> 6) + ((i0 & 63) << 3);
    const int p1 = (i1 >> 6) + ((i1 & 63) << 3);
    unsigned v0 = bcnt_pb[(size_t)p0 * NBUK + b];
    unsigned v1 = bcnt_pb[(size_t)p1 * NBUK + b];
    unsigned local = v0 + v1;
    s[tid] = local;
    __syncthreads();
    for (int off = 1; off < 256; off <<= 1) {
        unsigned t = (tid >= off) ? s[tid - off] : 0u;
        __syncthreads();
        s[tid] += t;
        __syncthreads();
    }
    unsigned run = s[tid] - local;
    partial_pb[(size_t)b * 512 + i0] = run;
    partial_pb[(size_t)b * 512 + i1] = run + v0;
    if (tid == 255) colsum[b] = s[255];
}

// ---------------------------------------------------------------------------
// K3: exclusive scan of colsum -> bucketBase[NBUK+1]
// ---------------------------------------------------------------------------
__global__ __launch_bounds__(256) void bucketScan_kernel(const unsigned* __restrict__ colsum,
                                                         int NBUK, int E,
                                                         unsigned* __restrict__ bucketBase) {
    __shared__ unsigned s[256];
    const int tid = threadIdx.x;
    unsigned v[4], local = 0;
#pragma unroll
    for (int j = 0; j < 4; j++) {
        int i = tid * 4 + j;
        v[j] = (i < NBUK) ? colsum[i] : 0u;
        local += v[j];
    }
    s[tid] = local;
    __syncthreads();
    for (int off = 1; off < 256; off <<= 1) {
        unsigned t = (tid >= off) ? s[tid - off] : 0u;
        __syncthreads();
        s[tid] += t;
        __syncthreads();
    }
    unsigned run = s[tid] - local;
#pragma unroll
    for (int j = 0; j < 4; j++) {
        int i = tid * 4 + j;
        if (i < NBUK) bucketBase[i] = run;
        run += v[j];
    }
    if (tid == 0) bucketBase[NBUK] = (unsigned)E;
}

// ---------------------------------------------------------------------------
// K4: fill with per-block private LDS cursors (no global atomics).
// i(p) = (p&7)*64 + (p>>3).
// ---------------------------------------------------------------------------
__global__ __launch_bounds__(256) void fill_kernel(const int* __restrict__ ei, int E,
                                                   int chunk, int NBUK,
                                                   const unsigned* __restrict__ partial_pb,
                                                   const unsigned* __restrict__ bucketBase,
                                                   unsigned* __restrict__ sorted) {
    __shared__ unsigned cur[MAXBUK];
    const int tid = threadIdx.x;
    const int p = blockIdx.x;
    const int i = (p & 7) * 64 + (p >> 3);
    for (int k = tid; k < NBUK; k += 256)
        cur[k] = bucketBase[k] + partial_pb[(size_t)k * 512 + i];
    __syncthreads();
    const int e0 = p * chunk;
    const int e1 = min(E, e0 + chunk);
    for (int e = e0 + tid; e < e1; e += 256) {
        int row = ei[e];
        int col = ei[E + e];
        unsigned pos = atomicAdd(&cur[col >> 7], 1u);
        sorted[pos] = (unsigned)row | ((unsigned)(col & 127) << 20);
    }
}

// ---------------------------------------------------------------------------
// K5: per-bucket counting sort + rsd + rowptr + vbar scale.
// Epilogue scales vbarb rows [b*128, b*128+128) by rsqrt(deg) in place.
// ---------------------------------------------------------------------------
__global__ __launch_bounds__(256) void sort_kernel(
    const unsigned* __restrict__ bucketBase, const unsigned* __restrict__ sorted,
    float* __restrict__ rsd, unsigned* __restrict__ rowptr,
    unsigned* __restrict__ sorted2, unsigned short* __restrict__ vbarb, int N)
{
    __shared__ unsigned h[128];
    __shared__ unsigned sc[128];
    __shared__ unsigned cur[128];
    __shared__ float rs_l[128];
    const int tid = threadIdx.x;
    const int b = blockIdx.x;
    if (tid < 128) h[tid] = 0u;
    __syncthreads();
    const unsigned s = bucketBase[b];
    const unsigned e = bucketBase[b + 1];
    for (unsigned p = s + (unsigned)tid; p < e; p += 256u)
        atomicAdd(&h[sorted[p] >> 20], 1u);
    __syncthreads();
    if (tid < 128) sc[tid] = h[tid];
    __syncthreads();
    for (int off = 1; off < 128; off <<= 1) {
        unsigned t = 0;
        if (tid < 128 && tid >= off) t = sc[tid - off];
        __syncthreads();
        if (tid < 128) sc[tid] += t;
        __syncthreads();
    }
    if (tid < 128) {
        unsigned ex = sc[tid] - h[tid];
        cur[tid] = ex;
        float rv = h[tid] ? rsqrtf((float)h[tid]) : 0.f;
        rs_l[tid] = rv;
        int n = b * 128 + tid;
        if (n < N) {
            rsd[n] = rv;
            rowptr[n] = s + ex;
        }
    }
    if (b == (int)gridDim.x - 1 && tid == 0) rowptr[N] = e;
    __syncthreads();
    for (unsigned p = s + (unsigned)tid; p < e; p += 256u) {
        unsigned m = sorted[p];
        unsigned pos = atomicAdd(&cur[m >> 20], 1u);
        sorted2[s + pos] = m & 0xFFFFFu;
    }
    // scale vbarb rows of this bucket in place: vbar2 = vbar * rsqrt(deg)
    const int nbase = b * 128;
#pragma unroll
    for (int it = 0; it < 16; it++) {
        int idx = it * 256 + tid;          // 0..4095
        int cl = idx >> 5, d = idx & 31;
        int n = nbase + cl;
        if (n < N) {
            size_t off = (size_t)n * 32 + d;
            vbarb[off] = (unsigned short)f2bf(bf2f(vbarb[off]) * rs_l[cl]);
        }
    }
}

// ---------------------------------------------------------------------------
// K6: per-node gather: out[n,d] = cst[d] + rsd[n] * sum_p bf2f(vbarb[row_p, d])
// ---------------------------------------------------------------------------
__global__ __launch_bounds__(256) void gather_kernel(
    const unsigned* __restrict__ rowptr, const unsigned* __restrict__ sorted2,
    const unsigned short* __restrict__ vbarb, const float* __restrict__ g_csum,
    const float* __restrict__ rsd, float* __restrict__ out, int N, float invN)
{
    const int tid = threadIdx.x;
    const int n = blockIdx.x * 8 + (tid >> 5);
    const int d = tid & 31;
    if (n >= N) return;
    const unsigned s = rowptr[n];
    const unsigned e = rowptr[n + 1];
    float acc = 0.f;
    for (unsigned p0 = s; p0 < e; p0 += 32) {
        const int cnt = (int)min(32u, e - p0);
        unsigned pe = p0 + (unsigned)d;
        if (pe >= e) pe = e - 1;
        int m = (int)sorted2[pe];
        int j = 0;
        for (; j + 7 < cnt; j += 8) {
            int r0 = __shfl(m, j + 0, 32);
            int r1 = __shfl(m, j + 1, 32);
            int r2 = __shfl(m, j + 2, 32);
            int r3 = __shfl(m, j + 3, 32);
            int r4 = __shfl(m, j + 4, 32);
            int r5 = __shfl(m, j + 5, 32);
            int r6 = __shfl(m, j + 6, 32);
            int r7 = __shfl(m, j + 7, 32);
            float f0 = bf2f(vbarb[(size_t)r0 * 32 + d]);
            float f1 = bf2f(vbarb[(size_t)r1 * 32 + d]);
            float f2 = bf2f(vbarb[(size_t)r2 * 32 + d]);
            float f3 = bf2f(vbarb[(size_t)r3 * 32 + d]);
            float f4 = bf2f(vbarb[(size_t)r4 * 32 + d]);
            float f5 = bf2f(vbarb[(size_t)r5 * 32 + d]);
            float f6 = bf2f(vbarb[(size_t)r6 * 32 + d]);
            float f7 = bf2f(vbarb[(size_t)r7 * 32 + d]);
            acc += ((f0 + f1) + (f2 + f3)) + ((f4 + f5) + (f6 + f7));
        }
        for (; j < cnt; j++) {
            int r0 = __shfl(m, j, 32);
            acc += bf2f(vbarb[(size_t)r0 * 32 + d]);
        }
    }
    out[(size_t)n * 32 + d] = g_csum[d] * invN + rsd[n] * acc;
}

// ---------------------------------------------------------------------------
extern "C" void kernel_launch(void* const* d_in, const int* in_sizes, int n_in,
                              void* d_out, int out_size, void* d_ws, size_t ws_size,
                              hipStream_t stream) {
    const float* xs = (const float*)d_in[1];
    const int*   ei = (const int*)d_in[2];
    const float* Wv = (const float*)d_in[7];
    const float* bv = (const float*)d_in[8];
    float* out = (float*)d_out;

    const int N = in_sizes[0] / 128;
    const int E = in_sizes[2] / 2;
    const int NBUK = (N + 127) >> 7;                 // 782
    const int chunk = (E + GRID_EDGE - 1) / GRID_EDGE;
    const int VB = 1563;                             // vbar blocks in fused kernel

    char* ws = (char*)d_ws;
    size_t o = 0;
    unsigned short* vbarb = (unsigned short*)(ws + o); o += (size_t)N * 32 * 2;
    o = (o + 15) & ~(size_t)15;
    float*    rsd        = (float*)(ws + o);    o += (size_t)N * 4;
    float*    g_csum     = (float*)(ws + o);    o += 32 * 4;
    unsigned* rowptr     = (unsigned*)(ws + o); o += (size_t)(N + 1) * 4;
    unsigned* bcnt_pb    = (unsigned*)(ws + o); o += (size_t)GRID_EDGE * NBUK * 4;
    unsigned* partial_pb = (unsigned*)(ws + o); o += (size_t)NBUK * 512 * 4;
    unsigned* colsum     = (unsigned*)(ws + o); o += (size_t)NBUK * 4;
    unsigned* bucketBase = (unsigned*)(ws + o); o += (size_t)(NBUK + 1) * 4;
    o = (o + 15) & ~(size_t)15;
    short*    WTB        = (short*)(ws + o);    o += 4096 * 2;
    unsigned* sorted     = (unsigned*)(ws + o); o += (size_t)E * 4;
    unsigned* sorted2    = (unsigned*)(ws + o); o += (size_t)E * 4;

    wt_kernel<<<2, 256, 0, stream>>>(Wv, WTB, g_csum);
    fused_kernel<<<VB + GRID_EDGE, 256, 0, stream>>>(xs, WTB, bv, vbarb, g_csum,
                                                     N, VB, ei, E, chunk, NBUK, bcnt_pb);
    scanPB_kernel<<<NBUK, 256, 0, stream>>>(bcnt_pb, NBUK, partial_pb, colsum);
    bucketScan_kernel<<<1, 256, 0, stream>>>(colsum, NBUK, E, bucketBase);
    fill_kernel<<<GRID_EDGE, 256, 0, stream>>>(ei, E, chunk, NBUK, partial_pb,
                                               bucketBase, sorted);
    sort_kernel<<<NBUK, 256, 0, stream>>>(bucketBase, sorted, rsd, rowptr,
                                          sorted2, vbarb, N);
    gather_kernel<<<(N + 7) / 8, 256, 0, stream>>>(rowptr, sorted2, vbarb, g_csum,
                                                   rsd, out, N, 1.0f / (float)N);
}